// Round 11
// baseline (173.202 us; speedup 1.0000x reference)
//
#include <hip/hip_runtime.h>
#include <hip/hip_bf16.h>

// Fused MHA block: y = LN(x @ attn + residual)
// B=4 S=1024 D=1024 H=16 DK=64. fp32 I/O, bf16 MFMA internally.
#define B_ 4
#define S_ 1024
#define D_ 1024
#define H_ 16
#define DK_ 64
#define MROWS (B_*S_)   // 4096

typedef short bf16x8 __attribute__((ext_vector_type(8)));
typedef float f32x4 __attribute__((ext_vector_type(4)));
typedef unsigned short u16;
typedef unsigned u32;
typedef u16 u16x4 __attribute__((ext_vector_type(4)));

__device__ __forceinline__ u16 f2bf(float f) {
    union { float f; unsigned u; } v; v.f = f;
    unsigned u = v.u;
    u += 0x7fff + ((u >> 16) & 1);   // RNE
    return (u16)(u >> 16);
}

__device__ __forceinline__ void gld_lds16(const u16* gp, u16* lp) {
    __builtin_amdgcn_global_load_lds(
        (const __attribute__((address_space(1))) void*)gp,
        (__attribute__((address_space(3))) void*)lp,
        16, 0, 0);
}

// ---------------------------------------------------------------------------
// Pack: fp32 -> bf16 for activations and weights (R6-verified).
// ---------------------------------------------------------------------------
__global__ __launch_bounds__(256) void pack_bf16(
    const float* __restrict__ q, const float* __restrict__ k, const float* __restrict__ v,
    const float* __restrict__ wq, const float* __restrict__ wk,
    const float* __restrict__ wv, const float* __restrict__ wo,
    u16* __restrict__ act_dst, u16* __restrict__ w_dst)
{
    const int NACT = 3 * MROWS * D_;
    const int NW   = 4 * D_ * D_;
    for (int c = blockIdx.x * blockDim.x + threadIdx.x;
         c < (NACT + NW) / 4; c += gridDim.x * blockDim.x) {
        int e = c * 4;
        const float* s; u16* d;
        if (e < NACT) {
            int t = e >> 22;
            int off = e & (4194304 - 1);
            s = (t == 0 ? q : t == 1 ? k : v) + off;
            d = act_dst + e;
        } else {
            int e2 = e - NACT;
            int t = e2 >> 20;
            int off = e2 & (1048576 - 1);
            s = (t == 0 ? wq : t == 1 ? wk : t == 2 ? wv : wo) + off;
            d = w_dst + e2;
        }
        float4 tv = *(const float4*)s;
        u16x4 o; o[0]=f2bf(tv.x); o[1]=f2bf(tv.y); o[2]=f2bf(tv.z); o[3]=f2bf(tv.w);
        *(u16x4*)d = o;
    }
}

// ---------------------------------------------------------------------------
// GEMM v4: A-frags DIRECT from global (distance-1 prefetch, two named reg
// sets, unroll-2) + B double-buffered in LDS via gld_lds. 1 barrier/K-step.
// A is linear in global => no swizzle on the A path; B path unchanged
// (verified swizzle involution). LDS = 2*128*64*2 = 32KB.
// VT: z==2 stores C transposed (Vt[d][token]).
// ---------------------------------------------------------------------------
template<int BM, bool EPI_RESID, bool VT>
__global__ __launch_bounds__(256) void gemm_fast(
    const u16* __restrict__ Ab, const u16* __restrict__ Wb,
    u16* __restrict__ Cb, float* __restrict__ Cf, const float* __restrict__ resid)
{
    constexpr int WN = (BM == 128) ? 2 : 4;
    constexpr int WCOLS = 128 / WN;
    constexpr int NR = WCOLS / 16;
    __shared__ u16 ldsB[2][128 * 64];

    const int gx = gridDim.x, gy = gridDim.y, gz = gridDim.z;
    const int nwg = gx * gy * gz;
    const int flat = blockIdx.x + gx * (blockIdx.y + gy * blockIdx.z);
    const int f = (flat & 7) * (nwg >> 3) + (flat >> 3);
    const int bx = f % gx;
    const int rem = f / gx;
    const int by = rem % gy;
    const int z = rem / gy;

    Ab += (size_t)z * MROWS * D_;
    Wb += (size_t)z * D_ * D_;
    const u16* CbT = Cb + (EPI_RESID ? 0 : (size_t)z * MROWS * D_);
    u16* Cbz = (u16*)CbT;

    const int tid = threadIdx.x, lane = tid & 63, wid = tid >> 6;
    const int wr = (BM == 128) ? (wid >> 1) : 0;
    const int wc = (BM == 128) ? (wid & 1) : wid;
    const int g = lane >> 4, ql = lane & 15;
    const int m0 = by * BM, n0 = bx * 128;
    const int wbase = wid * 64;

    // per-lane A base: row = m0 + wr*64 + ql, col = 8g ; frag(ks,m) at
    // + m*16 rows, + kt + 32ks cols. 16B contiguous per lane.
    const u16* Ap_ = Ab + (size_t)(m0 + wr * 64 + ql) * 1024 + 8 * g;

    auto loadA = [&](bf16x8 (&af)[2][4], int it) {
        const int kt = it * 64;
        #pragma unroll
        for (int ks = 0; ks < 2; ++ks)
            #pragma unroll
            for (int m = 0; m < 4; ++m)
                af[ks][m] = *(const bf16x8*)(Ap_ + (size_t)(m * 16) * 1024 + kt + 32 * ks);
    };
    auto stageB = [&](int p, int it) {
        const int kt = it * 64;
        #pragma unroll
        for (int j = 0; j < 4; ++j) {
            int ch = j * 256 + tid;
            int row = ch >> 3, c8 = (ch & 7) ^ (row & 7);
            gld_lds16(Wb + (size_t)(n0 + row) * 1024 + kt + c8 * 8,
                      &ldsB[p][(j * 256 + wbase) * 8]);
        }
    };

    f32x4 acc[4][NR] = {};

    auto compute = [&](bf16x8 (&af)[2][4], int p) {
        #pragma unroll
        for (int ks = 0; ks < 2; ++ks) {
            const int cb = ks * 32 + g * 8;
            bf16x8 bfr[NR];
            #pragma unroll
            for (int n = 0; n < NR; ++n) {
                int row = wc * WCOLS + n * 16 + ql;
                bfr[n] = *(const bf16x8*)(&ldsB[p][row * 64 + (cb ^ ((row & 7) << 3))]);
            }
            #pragma unroll
            for (int m = 0; m < 4; ++m)
                #pragma unroll
                for (int n = 0; n < NR; ++n)
                    acc[m][n] = __builtin_amdgcn_mfma_f32_16x16x32_bf16(
                        af[ks][m], bfr[n], acc[m][n], 0, 0, 0);
        }
    };

    bf16x8 afA[2][4], afB[2][4];
    loadA(afA, 0);
    stageB(0, 0);
    __syncthreads();    // drains vmcnt(0): afA + B0 landed

    #pragma unroll
    for (int p = 0; p < 8; ++p) {
        const int it = 2 * p;
        if (it + 1 < 16) { loadA(afB, it + 1); stageB(1, it + 1); }
        compute(afA, 0);
        __syncthreads();                         // afB + B1 landed; B0 reads done
        if (it + 2 < 16) { loadA(afA, it + 2); stageB(0, it + 2); }
        compute(afB, 1);
        if (it + 2 < 16) __syncthreads();        // afA + B0 landed; B1 reads done
    }

    // C/D map: col = lane&15, row = (lane>>4)*4 + reg
    if (VT && z == 2) {
        #pragma unroll
        for (int m = 0; m < 4; ++m)
            #pragma unroll
            for (int n = 0; n < NR; ++n) {
                u16x4 o;
                #pragma unroll
                for (int r = 0; r < 4; ++r) o[r] = f2bf(acc[m][n][r]);
                int grow = m0 + wr * 64 + m * 16 + g * 4;
                int gcol = n0 + wc * WCOLS + n * 16 + ql;
                *(u16x4*)(&Cbz[(size_t)gcol * MROWS + grow]) = o;
            }
    } else {
        #pragma unroll
        for (int m = 0; m < 4; ++m)
            #pragma unroll
            for (int n = 0; n < NR; ++n)
                #pragma unroll
                for (int r = 0; r < 4; ++r) {
                    int grow = m0 + wr * 64 + m * 16 + g * 4 + r;
                    int gcol = n0 + wc * WCOLS + n * 16 + ql;
                    if (EPI_RESID)
                        Cf[(size_t)grow * 1024 + gcol] = acc[m][n][r] + resid[(size_t)grow * 1024 + gcol];
                    else
                        Cbz[(size_t)grow * 1024 + gcol] = f2bf(acc[m][n][r]);
                }
    }
}

// ---------------------------------------------------------------------------
// Fallback GEMM (round-1 path), unchanged.
// ---------------------------------------------------------------------------
template<bool A_BF16, bool EPI_RESID>
__global__ __launch_bounds__(256) void gemm_bt(
    const void* __restrict__ Av, const float* __restrict__ Bw,
    u16* __restrict__ Cb, float* __restrict__ Cf,
    const float* __restrict__ resid, int M, int N, int K)
{
    __shared__ u16 lds[2][128 * 64];
    const int tid  = threadIdx.x;
    const int lane = tid & 63;
    const int wid  = tid >> 6;
    const int wr = wid >> 1, wc = wid & 1;
    const int m0 = blockIdx.y * 128, n0 = blockIdx.x * 128;

    f32x4 acc[4][4] = {};

    for (int kt = 0; kt < K; kt += 64) {
        #pragma unroll
        for (int j = 0; j < 8; ++j) {
            int idx4 = tid + 256 * j;
            int r = idx4 >> 4;
            int c = (idx4 & 15) * 4;
            u16x4 aw, bw;
            if (A_BF16) {
                const u16* Ab2 = (const u16*)Av;
                aw = *(const u16x4*)(Ab2 + (size_t)(m0 + r) * K + kt + c);
            } else {
                const float* Af = (const float*)Av;
                float4 t = *(const float4*)(Af + (size_t)(m0 + r) * K + kt + c);
                aw[0] = f2bf(t.x); aw[1] = f2bf(t.y); aw[2] = f2bf(t.z); aw[3] = f2bf(t.w);
            }
            {
                float4 t = *(const float4*)(Bw + (size_t)(n0 + r) * K + kt + c);
                bw[0] = f2bf(t.x); bw[1] = f2bf(t.y); bw[2] = f2bf(t.z); bw[3] = f2bf(t.w);
            }
            int sa = r * 64 + (c ^ ((r & 7) << 3));
            *(u16x4*)(&lds[0][sa]) = aw;
            *(u16x4*)(&lds[1][sa]) = bw;
        }
        __syncthreads();
        #pragma unroll
        for (int ks = 0; ks < 2; ++ks) {
            const int cb = ks * 32 + (lane >> 4) * 8;
            bf16x8 af[4], bfr[4];
            #pragma unroll
            for (int m = 0; m < 4; ++m) {
                int row = wr * 64 + m * 16 + (lane & 15);
                af[m] = *(const bf16x8*)(&lds[0][row * 64 + (cb ^ ((row & 7) << 3))]);
            }
            #pragma unroll
            for (int n = 0; n < 4; ++n) {
                int row = wc * 64 + n * 16 + (lane & 15);
                bfr[n] = *(const bf16x8*)(&lds[1][row * 64 + (cb ^ ((row & 7) << 3))]);
            }
            #pragma unroll
            for (int m = 0; m < 4; ++m)
                #pragma unroll
                for (int n = 0; n < 4; ++n)
                    acc[m][n] = __builtin_amdgcn_mfma_f32_16x16x32_bf16(
                        af[m], bfr[n], acc[m][n], 0, 0, 0);
        }
        __syncthreads();
    }

    #pragma unroll
    for (int m = 0; m < 4; ++m)
        #pragma unroll
        for (int n = 0; n < 4; ++n)
            #pragma unroll
            for (int r = 0; r < 4; ++r) {
                int grow = m0 + wr * 64 + m * 16 + (lane >> 4) * 4 + r;
                int gcol = n0 + wc * 64 + n * 16 + (lane & 15);
                float v = acc[m][n][r];
                if (EPI_RESID)
                    Cf[(size_t)grow * N + gcol] = v + resid[(size_t)grow * N + gcol];
                else
                    Cb[(size_t)grow * N + gcol] = f2bf(v);
            }
}

// ---------------------------------------------------------------------------
// Flash attention v6 (R9-verified): swapped QK^T, in-lane softmax,
// wave-private P, Vt-from-global, split-stage pipeline, Q-in-reg, defer-max.
// ---------------------------------------------------------------------------
__global__ __launch_bounds__(512, 4) void attn_fwd6(
    const u16* __restrict__ Qg, const u16* __restrict__ Kg,
    const u16* __restrict__ Vt, u16* __restrict__ Og)
{
    __shared__ u16 ks2[64 * 64];
    __shared__ u16 vsT[64 * 64];
    __shared__ u16 ps[128 * 64];

    const int tid = threadIdx.x, lane = tid & 63, w = tid >> 6;
    const int g = lane >> 4, ql = lane & 15;

    const int bid = blockIdx.x;
    const int f = (bid & 7) * 64 + (bid >> 3);
    const int qt = f & 7, h = (f >> 3) & 15, b = f >> 7;
    const int q0 = qt * 128;
    const size_t rbase = (size_t)b * S_;
    const int cb0 = h * DK_;

    bf16x8 qb[2];
    {
        const u16* qp = Qg + (rbase + q0 + w * 16 + ql) * D_ + cb0 + 8 * g;
        qb[0] = *(const bf16x8*)(qp);
        qb[1] = *(const bf16x8*)(qp + 32);
    }

    auto stage_k = [&](int kv0) {
        int row = tid >> 3, c8 = (tid & 7) ^ (row & 7);
        gld_lds16(Kg + (rbase + kv0 + row) * D_ + cb0 + c8 * 8, &ks2[w * 512]);
    };
    auto stage_v = [&](int kv0) {
        int row = tid >> 3, c8 = (tid & 7) ^ (row & 7);
        gld_lds16(Vt + (size_t)(cb0 + row) * MROWS + rbase + kv0 + c8 * 8, &vsT[w * 512]);
    };

    stage_k(0);
    stage_v(0);
    __syncthreads();

    float mrow = -1e30f, lrow = 0.f;
    f32x4 xacc[4] = {};

    for (int jt = 0; jt < 16; ++jt) {
        f32x4 sacc[4] = {};
        __builtin_amdgcn_s_setprio(1);
        #pragma unroll
        for (int ks = 0; ks < 2; ++ks) {
            #pragma unroll
            for (int n = 0; n < 4; ++n) {
                int krow = n * 16 + ql;
                int c = 32 * ks + 8 * g;
                bf16x8 kf = *(const bf16x8*)(&ks2[krow * 64 + (c ^ ((krow & 7) << 3))]);
                sacc[n] = __builtin_amdgcn_mfma_f32_16x16x32_bf16(kf, qb[ks], sacc[n], 0, 0, 0);
            }
        }
        __builtin_amdgcn_s_setprio(0);

        __syncthreads();
        if (jt < 15) stage_k((jt + 1) * 64);

        float mt = sacc[0][0];
        #pragma unroll
        for (int n = 0; n < 4; ++n)
            #pragma unroll
            for (int r = 0; r < 4; ++r) mt = fmaxf(mt, sacc[n][r]);
        mt = fmaxf(mt, __shfl_xor(mt, 16));
        mt = fmaxf(mt, __shfl_xor(mt, 32));
        if (!__all(mt * 0.125f - mrow <= 8.f)) {
            float mnew = fmaxf(mrow, mt * 0.125f);
            float alpha = __expf(mrow - mnew);
            mrow = mnew;
            lrow *= alpha;
            #pragma unroll
            for (int r = 0; r < 4; ++r) {
                float a_r = __shfl(alpha, 4 * g + r);
                #pragma unroll
                for (int n2 = 0; n2 < 4; ++n2) xacc[n2][r] *= a_r;
            }
        }
        float rsum = 0.f;
        u16 pb[16];
        #pragma unroll
        for (int n = 0; n < 4; ++n)
            #pragma unroll
            for (int r = 0; r < 4; ++r) {
                float p = __expf(sacc[n][r] * 0.125f - mrow);
                rsum += p;
                pb[n * 4 + r] = f2bf(p);
            }
        rsum += __shfl_xor(rsum, 16);
        rsum += __shfl_xor(rsum, 32);
        lrow += rsum;

        {
            const int q = w * 16 + ql;
            #pragma unroll
            for (int n = 0; n < 4; ++n) {
                int c = 16 * n + 4 * g;
                *(u16x4*)(&ps[q * 64 + (c ^ ((q & 7) << 3))]) = *(const u16x4*)(&pb[n * 4]);
            }
        }
        asm volatile("s_waitcnt lgkmcnt(0)" ::: "memory");
        __builtin_amdgcn_sched_barrier(0);

        bf16x8 pa[2];
        {
            const int q = w * 16 + ql;
            #pragma unroll
            for (int ks = 0; ks < 2; ++ks) {
                int c = 32 * ks + 8 * g;
                pa[ks] = *(const bf16x8*)(&ps[q * 64 + (c ^ ((q & 7) << 3))]);
            }
        }

        __builtin_amdgcn_s_setprio(1);
        #pragma unroll
        for (int ks = 0; ks < 2; ++ks)
            #pragma unroll
            for (int n2 = 0; n2 < 4; ++n2) {
                int vrow = n2 * 16 + ql;
                int c2 = 32 * ks + 8 * g;
                bf16x8 bv = *(const bf16x8*)(&vsT[vrow * 64 + (c2 ^ ((vrow & 7) << 3))]);
                xacc[n2] = __builtin_amdgcn_mfma_f32_16x16x32_bf16(pa[ks], bv, xacc[n2], 0, 0, 0);
            }
        __builtin_amdgcn_s_setprio(0);

        __syncthreads();
        if (jt < 15) stage_v((jt + 1) * 64);
    }

    float linv[4];
    #pragma unroll
    for (int r = 0; r < 4; ++r) linv[r] = 1.f / __shfl(lrow, 4 * g + r);
    #pragma unroll
    for (int n2 = 0; n2 < 4; ++n2)
        #pragma unroll
        for (int r = 0; r < 4; ++r) {
            int qrow = q0 + w * 16 + 4 * g + r;
            int col = cb0 + n2 * 16 + ql;
            Og[(rbase + qrow) * D_ + col] = f2bf(xacc[n2][r] * linv[r]);
        }
}

// ---------------------------------------------------------------------------
// Flash attention (R2-verified version) for the fallback path.
// ---------------------------------------------------------------------------
__global__ __launch_bounds__(256) void attn_fwd(
    const u16* __restrict__ Qg, const u16* __restrict__ Kg,
    const u16* __restrict__ Vg, u16* __restrict__ Og)
{
    __shared__ u16 qs[64 * 64], ks2[64 * 64], vt[64 * 64], ps[64 * 64];
    const int tid = threadIdx.x, lane = tid & 63, w = tid >> 6;
    const int b = blockIdx.z, h = blockIdx.y, q0 = blockIdx.x * 64;
    const size_t rbase = (size_t)b * S_;
    const int cb0 = h * DK_;

    #pragma unroll
    for (int j = 0; j < 4; ++j) {
        int idx4 = tid + 256 * j;
        int r = idx4 >> 4, c = (idx4 & 15) * 4;
        u16x4 t = *(const u16x4*)(Qg + (rbase + q0 + r) * D_ + cb0 + c);
        *(u16x4*)(&qs[r * 64 + (c ^ ((r & 7) << 3))]) = t;
    }

    float mrow[4], lrow[4];
    f32x4 xacc[4] = {};
    #pragma unroll
    for (int r = 0; r < 4; ++r) { mrow[r] = -1e30f; lrow[r] = 0.f; }

    for (int jt = 0; jt < 16; ++jt) {
        const int kv0 = jt * 64;
        __syncthreads();
        #pragma unroll
        for (int j = 0; j < 4; ++j) {
            int idx4 = tid + 256 * j;
            int r = idx4 >> 4, c = (idx4 & 15) * 4;
            u16x4 t = *(const u16x4*)(Kg + (rbase + kv0 + r) * D_ + cb0 + c);
            *(u16x4*)(&ks2[r * 64 + (c ^ ((r & 7) << 3))]) = t;
            u16x4 tv = *(const u16x4*)(Vg + (rbase + kv0 + r) * D_ + cb0 + c);
            #pragma unroll
            for (int jj = 0; jj < 4; ++jj) {
                int d = c + jj;
                vt[d * 64 + (r ^ ((d & 7) << 3))] = tv[jj];
            }
        }
        __syncthreads();

        f32x4 sacc[4] = {};
        #pragma unroll
        for (int ks = 0; ks < 2; ++ks) {
            const int cb = ks * 32 + (lane >> 4) * 8;
            int qrow = w * 16 + (lane & 15);
            bf16x8 aq = *(const bf16x8*)(&qs[qrow * 64 + (cb ^ ((qrow & 7) << 3))]);
            #pragma unroll
            for (int n = 0; n < 4; ++n) {
                int krow = n * 16 + (lane & 15);
                bf16x8 bk = *(const bf16x8*)(&ks2[krow * 64 + (cb ^ ((krow & 7) << 3))]);
                sacc[n] = __builtin_amdgcn_mfma_f32_16x16x32_bf16(aq, bk, sacc[n], 0, 0, 0);
            }
        }

        #pragma unroll
        for (int r = 0; r < 4; ++r) {
            float mx = fmaxf(fmaxf(sacc[0][r], sacc[1][r]),
                             fmaxf(sacc[2][r], sacc[3][r]));
            mx = fmaxf(mx, __shfl_xor(mx, 1));
            mx = fmaxf(mx, __shfl_xor(mx, 2));
            mx = fmaxf(mx, __shfl_xor(mx, 4));
            mx = fmaxf(mx, __shfl_xor(mx, 8));
            float mnew = fmaxf(mrow[r], mx * 0.125f);
            float alpha = __expf(mrow[r] - mnew);
            float p[4], rsum = 0.f;
            #pragma unroll
            for (int n = 0; n < 4; ++n) { p[n] = __expf(sacc[n][r] * 0.125f - mnew); rsum += p[n]; }
            rsum += __shfl_xor(rsum, 1);
            rsum += __shfl_xor(rsum, 2);
            rsum += __shfl_xor(rsum, 4);
            rsum += __shfl_xor(rsum, 8);
            lrow[r] = lrow[r] * alpha + rsum;
            mrow[r] = mnew;
            int qrow = w * 16 + (lane >> 4) * 4 + r;
            #pragma unroll
            for (int n = 0; n < 4; ++n) {
                xacc[n][r] *= alpha;
                int col = n * 16 + (lane & 15);
                ps[qrow * 64 + (col ^ ((qrow & 7) << 3))] = f2bf(p[n]);
            }
        }
        __syncthreads();

        #pragma unroll
        for (int ks = 0; ks < 2; ++ks) {
            const int cb = ks * 32 + (lane >> 4) * 8;
            int prow = w * 16 + (lane & 15);
            bf16x8 ap = *(const bf16x8*)(&ps[prow * 64 + (cb ^ ((prow & 7) << 3))]);
            #pragma unroll
            for (int n = 0; n < 4; ++n) {
                int vrow = n * 16 + (lane & 15);
                bf16x8 bv = *(const bf16x8*)(&vt[vrow * 64 + (cb ^ ((vrow & 7) << 3))]);
                xacc[n] = __builtin_amdgcn_mfma_f32_16x16x32_bf16(ap, bv, xacc[n], 0, 0, 0);
            }
        }
    }

    #pragma unroll
    for (int n = 0; n < 4; ++n)
        #pragma unroll
        for (int r = 0; r < 4; ++r) {
            int qrow = q0 + w * 16 + (lane >> 4) * 4 + r;
            int col = cb0 + n * 16 + (lane & 15);
            Og[(rbase + qrow) * D_ + col] = f2bf(xacc[n][r] / lrow[r]);
        }
}

// ---------------------------------------------------------------------------
// LayerNorm in-place on fp32 [4096][1024]: one block per row.
// ---------------------------------------------------------------------------
__global__ __launch_bounds__(256) void ln_inplace(
    float* __restrict__ Y, const float* __restrict__ g, const float* __restrict__ bt)
{
    __shared__ float red[2][4];
    const int row = blockIdx.x, tid = threadIdx.x;
    float4 v = *(const float4*)(Y + (size_t)row * D_ + tid * 4);
    float s = v.x + v.y + v.z + v.w;
    float q = v.x * v.x + v.y * v.y + v.z * v.z + v.w * v.w;
    #pragma unroll
    for (int m = 1; m < 64; m <<= 1) { s += __shfl_xor(s, m); q += __shfl_xor(q, m); }
    const int w = tid >> 6, lane = tid & 63;
    if (lane == 0) { red[0][w] = s; red[1][w] = q; }
    __syncthreads();
    s = red[0][0] + red[0][1] + red[0][2] + red[0][3];
    q = red[1][0] + red[1][1] + red[1][2] + red[1][3];
    float mu = s * (1.f / 1024.f);
    float var = q * (1.f / 1024.f) - mu * mu;
    float rstd = rsqrtf(var + 1e-6f);
    float4 gv = *(const float4*)(g + tid * 4);
    float4 bv = *(const float4*)(bt + tid * 4);
    v.x = (v.x - mu) * rstd * gv.x + bv.x;
    v.y = (v.y - mu) * rstd * gv.y + bv.y;
    v.z = (v.z - mu) * rstd * gv.z + bv.z;
    v.w = (v.w - mu) * rstd * gv.w + bv.w;
    *(float4*)(Y + (size_t)row * D_ + tid * 4) = v;
}

extern "C" void kernel_launch(void* const* d_in, const int* in_sizes, int n_in,
                              void* d_out, int out_size, void* d_ws, size_t ws_size,
                              hipStream_t stream)
{
    const float* query = (const float*)d_in[0];
    const float* key   = (const float*)d_in[1];
    const float* value = (const float*)d_in[2];
    const float* Wq    = (const float*)d_in[3];
    const float* Wk    = (const float*)d_in[4];
    const float* Wv    = (const float*)d_in[5];
    const float* Wo    = (const float*)d_in[6];
    const float* gamma = (const float*)d_in[7];
    const float* beta  = (const float*)d_in[8];
    float* out = (float*)d_out;

    const size_t ACT = (size_t)MROWS * D_;
    const size_t WSZ = (size_t)D_ * D_;
    const size_t NEED = (3 * ACT + 4 * WSZ + 3 * ACT) * 2;   // 58,720,256 B

    if (ws_size >= NEED) {
        u16* actb = (u16*)d_ws;
        u16* wb   = actb + 3 * ACT;
        u16* pb   = wb + 4 * WSZ;      // Qp | Kp | Vt (transposed)
        u16* Ap   = actb;               // alias: q-packed dead after QKV gemm

        pack_bf16<<<2048, 256, 0, stream>>>(query, key, value, Wq, Wk, Wv, Wo, actb, wb);
        gemm_fast<128, false, true><<<dim3(8, 32, 3), 256, 0, stream>>>(actb, wb, pb, nullptr, nullptr);
        attn_fwd6<<<512, 512, 0, stream>>>(pb, pb + ACT, pb + 2 * ACT, Ap);
        gemm_fast<64, true, false><<<dim3(8, 64, 1), 256, 0, stream>>>(Ap, wb + 3 * WSZ, nullptr, out, query);
        ln_inplace<<<MROWS, 256, 0, stream>>>(out, gamma, beta);
    } else {
        u16* Qp = (u16*)d_ws;
        u16* Kp = Qp + ACT;
        u16* Vp = Kp + ACT;
        u16* Ap = Vp + ACT;
        dim3 gg(D_ / 128, MROWS / 128);
        gemm_bt<false, false><<<gg, 256, 0, stream>>>(query, Wq, Qp, nullptr, nullptr, MROWS, D_, D_);
        gemm_bt<false, false><<<gg, 256, 0, stream>>>(key,   Wk, Kp, nullptr, nullptr, MROWS, D_, D_);
        gemm_bt<false, false><<<gg, 256, 0, stream>>>(value, Wv, Vp, nullptr, nullptr, MROWS, D_, D_);
        attn_fwd<<<dim3(S_ / 64, H_, B_), 256, 0, stream>>>(Qp, Kp, Vp, Ap);
        gemm_bt<true, true><<<gg, 256, 0, stream>>>(Ap, Wo, nullptr, out, query, MROWS, D_, D_);
        ln_inplace<<<MROWS, 256, 0, stream>>>(out, gamma, beta);
    }
}

// Round 12
// 121.530 us; speedup vs baseline: 1.4252x; 1.4252x over previous
//
#include <hip/hip_runtime.h>
#include <hip/hip_bf16.h>

// Fused MHA block: y = LN(x @ attn + residual)
// B=4 S=1024 D=1024 H=16 DK=64. fp32 I/O, bf16 MFMA internally.
#define B_ 4
#define S_ 1024
#define D_ 1024
#define H_ 16
#define DK_ 64
#define MROWS (B_*S_)   // 4096

typedef short bf16x8 __attribute__((ext_vector_type(8)));
typedef float f32x4 __attribute__((ext_vector_type(4)));
typedef unsigned short u16;
typedef unsigned u32;
typedef u16 u16x4 __attribute__((ext_vector_type(4)));

__device__ __forceinline__ u16 f2bf(float f) {
    union { float f; unsigned u; } v; v.f = f;
    unsigned u = v.u;
    u += 0x7fff + ((u >> 16) & 1);   // RNE
    return (u16)(u >> 16);
}

__device__ __forceinline__ void gld_lds16(const u16* gp, u16* lp) {
    __builtin_amdgcn_global_load_lds(
        (const __attribute__((address_space(1))) void*)gp,
        (__attribute__((address_space(3))) void*)lp,
        16, 0, 0);
}

// ---------------------------------------------------------------------------
// Pack v2: weights -> linear bf16 (unchanged). Activations (q,k,v) -> bf16 in
// FRAG-MAJOR layout A''[z][R64][kt][ks][m][lane=16g+ql][e8]:
//   element (row,col): R64=row>>6, m=(row>>4)&3, ql=row&15,
//                      kt=col>>6, ks=(col>>5)&1, g=(col>>3)&3, e8=col&7.
// Iteration is A''-major: writes coalesced; reads = 16 full 64B lines/wave.
// ---------------------------------------------------------------------------
__global__ __launch_bounds__(256) void pack_bf16(
    const float* __restrict__ q, const float* __restrict__ k, const float* __restrict__ v,
    const float* __restrict__ wq, const float* __restrict__ wk,
    const float* __restrict__ wv, const float* __restrict__ wo,
    u16* __restrict__ act_dst, u16* __restrict__ w_dst)
{
    const int NACTG = 3 * MROWS * D_ / 4;   // 3,145,728 granules (4 elems)
    const int NWG   = 4 * D_ * D_ / 4;
    for (int c = blockIdx.x * blockDim.x + threadIdx.x;
         c < NACTG + NWG; c += gridDim.x * blockDim.x) {
        if (c < NACTG) {
            int z  = c >> 20;
            int a2 = c & 0xFFFFF;
            int e4  = (a2 & 1) * 4;
            int lc  = (a2 >> 1) & 63;
            int g   = lc >> 4, ql = lc & 15;
            int m   = (a2 >> 7) & 3;
            int ks  = (a2 >> 9) & 1;
            int kt  = (a2 >> 10) & 15;
            int R64 = (a2 >> 14);           // 0..63
            int row = R64 * 64 + m * 16 + ql;
            int col = kt * 64 + ks * 32 + g * 8 + e4;
            const float* s = (z == 0 ? q : z == 1 ? k : v) + (size_t)row * D_ + col;
            float4 tv = *(const float4*)s;
            u16x4 o; o[0]=f2bf(tv.x); o[1]=f2bf(tv.y); o[2]=f2bf(tv.z); o[3]=f2bf(tv.w);
            *(u16x4*)(act_dst + (size_t)c * 4) = o;
        } else {
            int e2 = (c - NACTG) * 4;
            int t = e2 >> 20;
            int off = e2 & (1048576 - 1);
            const float* s = (t == 0 ? wq : t == 1 ? wk : t == 2 ? wv : wo) + off;
            float4 tv = *(const float4*)s;
            u16x4 o; o[0]=f2bf(tv.x); o[1]=f2bf(tv.y); o[2]=f2bf(tv.z); o[3]=f2bf(tv.w);
            *(u16x4*)(w_dst + e2) = o;
        }
    }
}

// ---------------------------------------------------------------------------
// QKV GEMM v5: A-frags direct from global in FRAG-MAJOR layout (64 lanes read
// 1KB contiguous per load — coalesced), distance-1 prefetch (afA/afB),
// B double-buffered in LDS via gld_lds. 1 barrier/K-step. LDS = 32KB.
// z==2 (V projection) stores C transposed (Vt[d][token]).
// ---------------------------------------------------------------------------
__global__ __launch_bounds__(256) void gemm_qkv(
    const u16* __restrict__ Ab, const u16* __restrict__ Wb,
    u16* __restrict__ Cb)
{
    __shared__ u16 ldsB[2][128 * 64];

    // XCD-chunked remap (nwg = 768, %8==0 -> bijective)
    const int gx = gridDim.x, gy = gridDim.y;
    const int nwg = gx * gy * gridDim.z;
    const int flat = blockIdx.x + gx * (blockIdx.y + gy * blockIdx.z);
    const int f = (flat & 7) * (nwg >> 3) + (flat >> 3);
    const int bx = f % gx;
    const int rem = f / gx;
    const int by = rem % gy;
    const int z = rem / gy;

    Ab += (size_t)z * MROWS * D_;
    Wb += (size_t)z * D_ * D_;

    const int tid = threadIdx.x, lane = tid & 63, wid = tid >> 6;
    const int wr = wid >> 1, wc = wid & 1;
    const int g = lane >> 4, ql = lane & 15;
    const int m0 = by * 128, n0 = bx * 128;
    const int wbase = wid * 64;

    // frag-major A base for this wave's 64-row group (R64 = m0/64 + wr):
    // chunk group (it,ks,m) at offset ((it*2+ks)*4+m)*512, lane stride 8.
    const u16* App = Ab + ((size_t)(m0 >> 6) + wr) * 65536 + (size_t)lane * 8;

    auto loadA = [&](bf16x8 (&af)[2][4], int it) {
        #pragma unroll
        for (int ks = 0; ks < 2; ++ks)
            #pragma unroll
            for (int m = 0; m < 4; ++m)
                af[ks][m] = *(const bf16x8*)(App + (size_t)(((it * 2 + ks) * 4 + m)) * 512);
    };
    auto stageB = [&](int p, int it) {
        const int kt = it * 64;
        #pragma unroll
        for (int j = 0; j < 4; ++j) {
            int ch = j * 256 + tid;
            int row = ch >> 3, c8 = (ch & 7) ^ (row & 7);
            gld_lds16(Wb + (size_t)(n0 + row) * 1024 + kt + c8 * 8,
                      &ldsB[p][(j * 256 + wbase) * 8]);
        }
    };

    f32x4 acc[4][4] = {};

    auto compute = [&](bf16x8 (&af)[2][4], int p) {
        #pragma unroll
        for (int ks = 0; ks < 2; ++ks) {
            const int cb = ks * 32 + g * 8;
            bf16x8 bfr[4];
            #pragma unroll
            for (int n = 0; n < 4; ++n) {
                int row = wc * 64 + n * 16 + ql;
                bfr[n] = *(const bf16x8*)(&ldsB[p][row * 64 + (cb ^ ((row & 7) << 3))]);
            }
            #pragma unroll
            for (int m = 0; m < 4; ++m)
                #pragma unroll
                for (int n = 0; n < 4; ++n)
                    acc[m][n] = __builtin_amdgcn_mfma_f32_16x16x32_bf16(
                        af[ks][m], bfr[n], acc[m][n], 0, 0, 0);
        }
    };

    bf16x8 afA[2][4], afB[2][4];
    loadA(afA, 0);
    stageB(0, 0);
    __syncthreads();    // drains vmcnt(0): afA + B0 landed

    #pragma unroll
    for (int p = 0; p < 8; ++p) {
        const int it = 2 * p;
        if (it + 1 < 16) { loadA(afB, it + 1); stageB(1, it + 1); }
        compute(afA, 0);
        __syncthreads();                         // afB + B1 landed; B0 reads done
        if (it + 2 < 16) { loadA(afA, it + 2); stageB(0, it + 2); }
        compute(afB, 1);
        if (it + 2 < 16) __syncthreads();        // afA + B0 landed; B1 reads done
    }

    // C/D map: col = lane&15, row = (lane>>4)*4 + reg
    if (z == 2) {
        u16* Cz = Cb + 2 * (size_t)MROWS * D_;
        #pragma unroll
        for (int m = 0; m < 4; ++m)
            #pragma unroll
            for (int n = 0; n < 4; ++n) {
                u16x4 o;
                #pragma unroll
                for (int r = 0; r < 4; ++r) o[r] = f2bf(acc[m][n][r]);
                int grow = m0 + wr * 64 + m * 16 + g * 4;   // token
                int gcol = n0 + wc * 64 + n * 16 + ql;      // d
                *(u16x4*)(&Cz[(size_t)gcol * MROWS + grow]) = o;
            }
    } else {
        u16* Cz = Cb + (size_t)z * MROWS * D_;
        #pragma unroll
        for (int m = 0; m < 4; ++m)
            #pragma unroll
            for (int n = 0; n < 4; ++n)
                #pragma unroll
                for (int r = 0; r < 4; ++r) {
                    int grow = m0 + wr * 64 + m * 16 + g * 4 + r;
                    int gcol = n0 + wc * 64 + n * 16 + ql;
                    Cz[(size_t)grow * 1024 + gcol] = f2bf(acc[m][n][r]);
                }
    }
}

// ---------------------------------------------------------------------------
// GEMM v3 (R10-verified): A-reg-preload from LDS + B-double-buffer.
// Used for the Wo projection (BM=64, residual epilogue, row-major A).
// ---------------------------------------------------------------------------
template<int BM, bool EPI_RESID, bool VT>
__global__ __launch_bounds__(256) void gemm_fast(
    const u16* __restrict__ Ab, const u16* __restrict__ Wb,
    u16* __restrict__ Cb, float* __restrict__ Cf, const float* __restrict__ resid)
{
    constexpr int WN = (BM == 128) ? 2 : 4;
    constexpr int WCOLS = 128 / WN;
    constexpr int NR = WCOLS / 16;
    __shared__ u16 ldsA[BM * 64];
    __shared__ u16 ldsB[2][128 * 64];

    const int gx = gridDim.x, gy = gridDim.y, gz = gridDim.z;
    const int nwg = gx * gy * gz;
    const int flat = blockIdx.x + gx * (blockIdx.y + gy * blockIdx.z);
    const int f = (flat & 7) * (nwg >> 3) + (flat >> 3);
    const int bx = f % gx;
    const int rem = f / gx;
    const int by = rem % gy;
    const int z = rem / gy;

    Ab += (size_t)z * MROWS * D_;
    Wb += (size_t)z * D_ * D_;
    const u16* CbT = Cb + (EPI_RESID ? 0 : (size_t)z * MROWS * D_);
    u16* Cbz = (u16*)CbT;

    const int tid = threadIdx.x, lane = tid & 63, wid = tid >> 6;
    const int wr = (BM == 128) ? (wid >> 1) : 0;
    const int wc = (BM == 128) ? (wid & 1) : wid;
    const int m0 = by * BM, n0 = bx * 128;
    const int wbase = wid * 64;

    auto stageA = [&](int it) {
        const int kt = it * 64;
        #pragma unroll
        for (int j = 0; j < BM / 32; ++j) {
            int ch = j * 256 + tid;
            int row = ch >> 3, c8 = (ch & 7) ^ (row & 7);
            gld_lds16(Ab + (size_t)(m0 + row) * 1024 + kt + c8 * 8,
                      &ldsA[(j * 256 + wbase) * 8]);
        }
    };
    auto stageB = [&](int p, int it) {
        const int kt = it * 64;
        #pragma unroll
        for (int j = 0; j < 4; ++j) {
            int ch = j * 256 + tid;
            int row = ch >> 3, c8 = (ch & 7) ^ (row & 7);
            gld_lds16(Wb + (size_t)(n0 + row) * 1024 + kt + c8 * 8,
                      &ldsB[p][(j * 256 + wbase) * 8]);
        }
    };

    f32x4 acc[4][NR] = {};

    stageA(0);
    stageB(0, 0);
    __syncthreads();

    for (int it = 0; it < 16; ++it) {
        const int bcur = it & 1;

        bf16x8 af[2][4];
        #pragma unroll
        for (int ks = 0; ks < 2; ++ks) {
            const int cb = ks * 32 + (lane >> 4) * 8;
            #pragma unroll
            for (int m = 0; m < 4; ++m) {
                int row = wr * 64 + m * 16 + (lane & 15);
                af[ks][m] = *(const bf16x8*)(&ldsA[row * 64 + (cb ^ ((row & 7) << 3))]);
            }
        }
        __syncthreads();                 // all waves' A reads retired

        if (it < 15) {
            stageA(it + 1);
            stageB(bcur ^ 1, it + 1);
        }
        __builtin_amdgcn_sched_barrier(0);

        #pragma unroll
        for (int ks = 0; ks < 2; ++ks) {
            const int cb = ks * 32 + (lane >> 4) * 8;
            bf16x8 bfr[NR];
            #pragma unroll
            for (int n = 0; n < NR; ++n) {
                int row = wc * WCOLS + n * 16 + (lane & 15);
                bfr[n] = *(const bf16x8*)(&ldsB[bcur][row * 64 + (cb ^ ((row & 7) << 3))]);
            }
            #pragma unroll
            for (int m = 0; m < 4; ++m)
                #pragma unroll
                for (int n = 0; n < NR; ++n)
                    acc[m][n] = __builtin_amdgcn_mfma_f32_16x16x32_bf16(
                        af[ks][m], bfr[n], acc[m][n], 0, 0, 0);
        }

        __syncthreads();
    }

    if (VT && z == 2) {
        #pragma unroll
        for (int m = 0; m < 4; ++m)
            #pragma unroll
            for (int n = 0; n < NR; ++n) {
                u16x4 o;
                #pragma unroll
                for (int r = 0; r < 4; ++r) o[r] = f2bf(acc[m][n][r]);
                int grow = m0 + wr * 64 + m * 16 + (lane >> 4) * 4;
                int gcol = n0 + wc * WCOLS + n * 16 + (lane & 15);
                *(u16x4*)(&Cbz[(size_t)gcol * MROWS + grow]) = o;
            }
    } else {
        #pragma unroll
        for (int m = 0; m < 4; ++m)
            #pragma unroll
            for (int n = 0; n < NR; ++n)
                #pragma unroll
                for (int r = 0; r < 4; ++r) {
                    int grow = m0 + wr * 64 + m * 16 + (lane >> 4) * 4 + r;
                    int gcol = n0 + wc * WCOLS + n * 16 + (lane & 15);
                    if (EPI_RESID)
                        Cf[(size_t)grow * 1024 + gcol] = acc[m][n][r] + resid[(size_t)grow * 1024 + gcol];
                    else
                        Cbz[(size_t)grow * 1024 + gcol] = f2bf(acc[m][n][r]);
                }
    }
}

// ---------------------------------------------------------------------------
// Fallback GEMM (round-1 path), unchanged.
// ---------------------------------------------------------------------------
template<bool A_BF16, bool EPI_RESID>
__global__ __launch_bounds__(256) void gemm_bt(
    const void* __restrict__ Av, const float* __restrict__ Bw,
    u16* __restrict__ Cb, float* __restrict__ Cf,
    const float* __restrict__ resid, int M, int N, int K)
{
    __shared__ u16 lds[2][128 * 64];
    const int tid  = threadIdx.x;
    const int lane = tid & 63;
    const int wid  = tid >> 6;
    const int wr = wid >> 1, wc = wid & 1;
    const int m0 = blockIdx.y * 128, n0 = blockIdx.x * 128;

    f32x4 acc[4][4] = {};

    for (int kt = 0; kt < K; kt += 64) {
        #pragma unroll
        for (int j = 0; j < 8; ++j) {
            int idx4 = tid + 256 * j;
            int r = idx4 >> 4;
            int c = (idx4 & 15) * 4;
            u16x4 aw, bw;
            if (A_BF16) {
                const u16* Ab2 = (const u16*)Av;
                aw = *(const u16x4*)(Ab2 + (size_t)(m0 + r) * K + kt + c);
            } else {
                const float* Af = (const float*)Av;
                float4 t = *(const float4*)(Af + (size_t)(m0 + r) * K + kt + c);
                aw[0] = f2bf(t.x); aw[1] = f2bf(t.y); aw[2] = f2bf(t.z); aw[3] = f2bf(t.w);
            }
            {
                float4 t = *(const float4*)(Bw + (size_t)(n0 + r) * K + kt + c);
                bw[0] = f2bf(t.x); bw[1] = f2bf(t.y); bw[2] = f2bf(t.z); bw[3] = f2bf(t.w);
            }
            int sa = r * 64 + (c ^ ((r & 7) << 3));
            *(u16x4*)(&lds[0][sa]) = aw;
            *(u16x4*)(&lds[1][sa]) = bw;
        }
        __syncthreads();
        #pragma unroll
        for (int ks = 0; ks < 2; ++ks) {
            const int cb = ks * 32 + (lane >> 4) * 8;
            bf16x8 af[4], bfr[4];
            #pragma unroll
            for (int m = 0; m < 4; ++m) {
                int row = wr * 64 + m * 16 + (lane & 15);
                af[m] = *(const bf16x8*)(&lds[0][row * 64 + (cb ^ ((row & 7) << 3))]);
            }
            #pragma unroll
            for (int n = 0; n < 4; ++n) {
                int row = wc * 64 + n * 16 + (lane & 15);
                bfr[n] = *(const bf16x8*)(&lds[1][row * 64 + (cb ^ ((row & 7) << 3))]);
            }
            #pragma unroll
            for (int m = 0; m < 4; ++m)
                #pragma unroll
                for (int n = 0; n < 4; ++n)
                    acc[m][n] = __builtin_amdgcn_mfma_f32_16x16x32_bf16(
                        af[m], bfr[n], acc[m][n], 0, 0, 0);
        }
        __syncthreads();
    }

    #pragma unroll
    for (int m = 0; m < 4; ++m)
        #pragma unroll
        for (int n = 0; n < 4; ++n)
            #pragma unroll
            for (int r = 0; r < 4; ++r) {
                int grow = m0 + wr * 64 + m * 16 + (lane >> 4) * 4 + r;
                int gcol = n0 + wc * 64 + n * 16 + (lane & 15);
                float v = acc[m][n][r];
                if (EPI_RESID)
                    Cf[(size_t)grow * N + gcol] = v + resid[(size_t)grow * N + gcol];
                else
                    Cb[(size_t)grow * N + gcol] = f2bf(v);
            }
}

// ---------------------------------------------------------------------------
// Flash attention v6 (R9-verified): swapped QK^T, in-lane softmax,
// wave-private P, Vt-from-global, split-stage pipeline, Q-in-reg, defer-max.
// ---------------------------------------------------------------------------
__global__ __launch_bounds__(512, 4) void attn_fwd6(
    const u16* __restrict__ Qg, const u16* __restrict__ Kg,
    const u16* __restrict__ Vt, u16* __restrict__ Og)
{
    __shared__ u16 ks2[64 * 64];
    __shared__ u16 vsT[64 * 64];
    __shared__ u16 ps[128 * 64];

    const int tid = threadIdx.x, lane = tid & 63, w = tid >> 6;
    const int g = lane >> 4, ql = lane & 15;

    const int bid = blockIdx.x;
    const int f = (bid & 7) * 64 + (bid >> 3);
    const int qt = f & 7, h = (f >> 3) & 15, b = f >> 7;
    const int q0 = qt * 128;
    const size_t rbase = (size_t)b * S_;
    const int cb0 = h * DK_;

    bf16x8 qb[2];
    {
        const u16* qp = Qg + (rbase + q0 + w * 16 + ql) * D_ + cb0 + 8 * g;
        qb[0] = *(const bf16x8*)(qp);
        qb[1] = *(const bf16x8*)(qp + 32);
    }

    auto stage_k = [&](int kv0) {
        int row = tid >> 3, c8 = (tid & 7) ^ (row & 7);
        gld_lds16(Kg + (rbase + kv0 + row) * D_ + cb0 + c8 * 8, &ks2[w * 512]);
    };
    auto stage_v = [&](int kv0) {
        int row = tid >> 3, c8 = (tid & 7) ^ (row & 7);
        gld_lds16(Vt + (size_t)(cb0 + row) * MROWS + rbase + kv0 + c8 * 8, &vsT[w * 512]);
    };

    stage_k(0);
    stage_v(0);
    __syncthreads();

    float mrow = -1e30f, lrow = 0.f;
    f32x4 xacc[4] = {};

    for (int jt = 0; jt < 16; ++jt) {
        f32x4 sacc[4] = {};
        __builtin_amdgcn_s_setprio(1);
        #pragma unroll
        for (int ks = 0; ks < 2; ++ks) {
            #pragma unroll
            for (int n = 0; n < 4; ++n) {
                int krow = n * 16 + ql;
                int c = 32 * ks + 8 * g;
                bf16x8 kf = *(const bf16x8*)(&ks2[krow * 64 + (c ^ ((krow & 7) << 3))]);
                sacc[n] = __builtin_amdgcn_mfma_f32_16x16x32_bf16(kf, qb[ks], sacc[n], 0, 0, 0);
            }
        }
        __builtin_amdgcn_s_setprio(0);

        __syncthreads();
        if (jt < 15) stage_k((jt + 1) * 64);

        float mt = sacc[0][0];
        #pragma unroll
        for (int n = 0; n < 4; ++n)
            #pragma unroll
            for (int r = 0; r < 4; ++r) mt = fmaxf(mt, sacc[n][r]);
        mt = fmaxf(mt, __shfl_xor(mt, 16));
        mt = fmaxf(mt, __shfl_xor(mt, 32));
        if (!__all(mt * 0.125f - mrow <= 8.f)) {
            float mnew = fmaxf(mrow, mt * 0.125f);
            float alpha = __expf(mrow - mnew);
            mrow = mnew;
            lrow *= alpha;
            #pragma unroll
            for (int r = 0; r < 4; ++r) {
                float a_r = __shfl(alpha, 4 * g + r);
                #pragma unroll
                for (int n2 = 0; n2 < 4; ++n2) xacc[n2][r] *= a_r;
            }
        }
        float rsum = 0.f;
        u16 pb[16];
        #pragma unroll
        for (int n = 0; n < 4; ++n)
            #pragma unroll
            for (int r = 0; r < 4; ++r) {
                float p = __expf(sacc[n][r] * 0.125f - mrow);
                rsum += p;
                pb[n * 4 + r] = f2bf(p);
            }
        rsum += __shfl_xor(rsum, 16);
        rsum += __shfl_xor(rsum, 32);
        lrow += rsum;

        {
            const int q = w * 16 + ql;
            #pragma unroll
            for (int n = 0; n < 4; ++n) {
                int c = 16 * n + 4 * g;
                *(u16x4*)(&ps[q * 64 + (c ^ ((q & 7) << 3))]) = *(const u16x4*)(&pb[n * 4]);
            }
        }
        asm volatile("s_waitcnt lgkmcnt(0)" ::: "memory");
        __builtin_amdgcn_sched_barrier(0);

        bf16x8 pa[2];
        {
            const int q = w * 16 + ql;
            #pragma unroll
            for (int ks = 0; ks < 2; ++ks) {
                int c = 32 * ks + 8 * g;
                pa[ks] = *(const bf16x8*)(&ps[q * 64 + (c ^ ((q & 7) << 3))]);
            }
        }

        __builtin_amdgcn_s_setprio(1);
        #pragma unroll
        for (int ks = 0; ks < 2; ++ks)
            #pragma unroll
            for (int n2 = 0; n2 < 4; ++n2) {
                int vrow = n2 * 16 + ql;
                int c2 = 32 * ks + 8 * g;
                bf16x8 bv = *(const bf16x8*)(&vsT[vrow * 64 + (c2 ^ ((vrow & 7) << 3))]);
                xacc[n2] = __builtin_amdgcn_mfma_f32_16x16x32_bf16(pa[ks], bv, xacc[n2], 0, 0, 0);
            }
        __builtin_amdgcn_s_setprio(0);

        __syncthreads();
        if (jt < 15) stage_v((jt + 1) * 64);
    }

    float linv[4];
    #pragma unroll
    for (int r = 0; r < 4; ++r) linv[r] = 1.f / __shfl(lrow, 4 * g + r);
    #pragma unroll
    for (int n2 = 0; n2 < 4; ++n2)
        #pragma unroll
        for (int r = 0; r < 4; ++r) {
            int qrow = q0 + w * 16 + 4 * g + r;
            int col = cb0 + n2 * 16 + ql;
            Og[(rbase + qrow) * D_ + col] = f2bf(xacc[n2][r] * linv[r]);
        }
}

// ---------------------------------------------------------------------------
// Flash attention (R2-verified version) for the fallback path.
// ---------------------------------------------------------------------------
__global__ __launch_bounds__(256) void attn_fwd(
    const u16* __restrict__ Qg, const u16* __restrict__ Kg,
    const u16* __restrict__ Vg, u16* __restrict__ Og)
{
    __shared__ u16 qs[64 * 64], ks2[64 * 64], vt[64 * 64], ps[64 * 64];
    const int tid = threadIdx.x, lane = tid & 63, w = tid >> 6;
    const int b = blockIdx.z, h = blockIdx.y, q0 = blockIdx.x * 64;
    const size_t rbase = (size_t)b * S_;
    const int cb0 = h * DK_;

    #pragma unroll
    for (int j = 0; j < 4; ++j) {
        int idx4 = tid + 256 * j;
        int r = idx4 >> 4, c = (idx4 & 15) * 4;
        u16x4 t = *(const u16x4*)(Qg + (rbase + q0 + r) * D_ + cb0 + c);
        *(u16x4*)(&qs[r * 64 + (c ^ ((r & 7) << 3))]) = t;
    }

    float mrow[4], lrow[4];
    f32x4 xacc[4] = {};
    #pragma unroll
    for (int r = 0; r < 4; ++r) { mrow[r] = -1e30f; lrow[r] = 0.f; }

    for (int jt = 0; jt < 16; ++jt) {
        const int kv0 = jt * 64;
        __syncthreads();
        #pragma unroll
        for (int j = 0; j < 4; ++j) {
            int idx4 = tid + 256 * j;
            int r = idx4 >> 4, c = (idx4 & 15) * 4;
            u16x4 t = *(const u16x4*)(Kg + (rbase + kv0 + r) * D_ + cb0 + c);
            *(u16x4*)(&ks2[r * 64 + (c ^ ((r & 7) << 3))]) = t;
            u16x4 tv = *(const u16x4*)(Vg + (rbase + kv0 + r) * D_ + cb0 + c);
            #pragma unroll
            for (int jj = 0; jj < 4; ++jj) {
                int d = c + jj;
                vt[d * 64 + (r ^ ((d & 7) << 3))] = tv[jj];
            }
        }
        __syncthreads();

        f32x4 sacc[4] = {};
        #pragma unroll
        for (int ks = 0; ks < 2; ++ks) {
            const int cb = ks * 32 + (lane >> 4) * 8;
            int qrow = w * 16 + (lane & 15);
            bf16x8 aq = *(const bf16x8*)(&qs[qrow * 64 + (cb ^ ((qrow & 7) << 3))]);
            #pragma unroll
            for (int n = 0; n < 4; ++n) {
                int krow = n * 16 + (lane & 15);
                bf16x8 bk = *(const bf16x8*)(&ks2[krow * 64 + (cb ^ ((krow & 7) << 3))]);
                sacc[n] = __builtin_amdgcn_mfma_f32_16x16x32_bf16(aq, bk, sacc[n], 0, 0, 0);
            }
        }

        #pragma unroll
        for (int r = 0; r < 4; ++r) {
            float mx = fmaxf(fmaxf(sacc[0][r], sacc[1][r]),
                             fmaxf(sacc[2][r], sacc[3][r]));
            mx = fmaxf(mx, __shfl_xor(mx, 1));
            mx = fmaxf(mx, __shfl_xor(mx, 2));
            mx = fmaxf(mx, __shfl_xor(mx, 4));
            mx = fmaxf(mx, __shfl_xor(mx, 8));
            float mnew = fmaxf(mrow[r], mx * 0.125f);
            float alpha = __expf(mrow[r] - mnew);
            float p[4], rsum = 0.f;
            #pragma unroll
            for (int n = 0; n < 4; ++n) { p[n] = __expf(sacc[n][r] * 0.125f - mnew); rsum += p[n]; }
            rsum += __shfl_xor(rsum, 1);
            rsum += __shfl_xor(rsum, 2);
            rsum += __shfl_xor(rsum, 4);
            rsum += __shfl_xor(rsum, 8);
            lrow[r] = lrow[r] * alpha + rsum;
            mrow[r] = mnew;
            int qrow = w * 16 + (lane >> 4) * 4 + r;
            #pragma unroll
            for (int n = 0; n < 4; ++n) {
                xacc[n][r] *= alpha;
                int col = n * 16 + (lane & 15);
                ps[qrow * 64 + (col ^ ((qrow & 7) << 3))] = f2bf(p[n]);
            }
        }
        __syncthreads();

        #pragma unroll
        for (int ks = 0; ks < 2; ++ks) {
            const int cb = ks * 32 + (lane >> 4) * 8;
            int prow = w * 16 + (lane & 15);
            bf16x8 ap = *(const bf16x8*)(&ps[prow * 64 + (cb ^ ((prow & 7) << 3))]);
            #pragma unroll
            for (int n = 0; n < 4; ++n) {
                int vrow = n * 16 + (lane & 15);
                bf16x8 bv = *(const bf16x8*)(&vt[vrow * 64 + (cb ^ ((vrow & 7) << 3))]);
                xacc[n] = __builtin_amdgcn_mfma_f32_16x16x32_bf16(ap, bv, xacc[n], 0, 0, 0);
            }
        }
    }

    #pragma unroll
    for (int n = 0; n < 4; ++n)
        #pragma unroll
        for (int r = 0; r < 4; ++r) {
            int qrow = q0 + w * 16 + (lane >> 4) * 4 + r;
            int col = cb0 + n * 16 + (lane & 15);
            Og[(rbase + qrow) * D_ + col] = f2bf(xacc[n][r] / lrow[r]);
        }
}

// ---------------------------------------------------------------------------
// LayerNorm in-place on fp32 [4096][1024]: one block per row.
// ---------------------------------------------------------------------------
__global__ __launch_bounds__(256) void ln_inplace(
    float* __restrict__ Y, const float* __restrict__ g, const float* __restrict__ bt)
{
    __shared__ float red[2][4];
    const int row = blockIdx.x, tid = threadIdx.x;
    float4 v = *(const float4*)(Y + (size_t)row * D_ + tid * 4);
    float s = v.x + v.y + v.z + v.w;
    float q = v.x * v.x + v.y * v.y + v.z * v.z + v.w * v.w;
    #pragma unroll
    for (int m = 1; m < 64; m <<= 1) { s += __shfl_xor(s, m); q += __shfl_xor(q, m); }
    const int w = tid >> 6, lane = tid & 63;
    if (lane == 0) { red[0][w] = s; red[1][w] = q; }
    __syncthreads();
    s = red[0][0] + red[0][1] + red[0][2] + red[0][3];
    q = red[1][0] + red[1][1] + red[1][2] + red[1][3];
    float mu = s * (1.f / 1024.f);
    float var = q * (1.f / 1024.f) - mu * mu;
    float rstd = rsqrtf(var + 1e-6f);
    float4 gv = *(const float4*)(g + tid * 4);
    float4 bv = *(const float4*)(bt + tid * 4);
    v.x = (v.x - mu) * rstd * gv.x + bv.x;
    v.y = (v.y - mu) * rstd * gv.y + bv.y;
    v.z = (v.z - mu) * rstd * gv.z + bv.z;
    v.w = (v.w - mu) * rstd * gv.w + bv.w;
    *(float4*)(Y + (size_t)row * D_ + tid * 4) = v;
}

extern "C" void kernel_launch(void* const* d_in, const int* in_sizes, int n_in,
                              void* d_out, int out_size, void* d_ws, size_t ws_size,
                              hipStream_t stream)
{
    const float* query = (const float*)d_in[0];
    const float* key   = (const float*)d_in[1];
    const float* value = (const float*)d_in[2];
    const float* Wq    = (const float*)d_in[3];
    const float* Wk    = (const float*)d_in[4];
    const float* Wv    = (const float*)d_in[5];
    const float* Wo    = (const float*)d_in[6];
    const float* gamma = (const float*)d_in[7];
    const float* beta  = (const float*)d_in[8];
    float* out = (float*)d_out;

    const size_t ACT = (size_t)MROWS * D_;
    const size_t WSZ = (size_t)D_ * D_;
    const size_t NEED = (3 * ACT + 4 * WSZ + 3 * ACT) * 2;   // 58,720,256 B

    if (ws_size >= NEED) {
        u16* actb = (u16*)d_ws;        // q,k,v in FRAG-MAJOR layout
        u16* wb   = actb + 3 * ACT;
        u16* pb   = wb + 4 * WSZ;      // Qp | Kp | Vt (transposed)
        u16* Ap   = actb;               // alias: q-packed dead after QKV gemm

        pack_bf16<<<2048, 256, 0, stream>>>(query, key, value, Wq, Wk, Wv, Wo, actb, wb);
        gemm_qkv<<<dim3(8, 32, 3), 256, 0, stream>>>(actb, wb, pb);
        attn_fwd6<<<512, 512, 0, stream>>>(pb, pb + ACT, pb + 2 * ACT, Ap);
        gemm_fast<64, true, false><<<dim3(8, 64, 1), 256, 0, stream>>>(Ap, wb + 3 * WSZ, nullptr, out, query);
        ln_inplace<<<MROWS, 256, 0, stream>>>(out, gamma, beta);
    } else {
        u16* Qp = (u16*)d_ws;
        u16* Kp = Qp + ACT;
        u16* Vp = Kp + ACT;
        u16* Ap = Vp + ACT;
        dim3 gg(D_ / 128, MROWS / 128);
        gemm_bt<false, false><<<gg, 256, 0, stream>>>(query, Wq, Qp, nullptr, nullptr, MROWS, D_, D_);
        gemm_bt<false, false><<<gg, 256, 0, stream>>>(key,   Wk, Kp, nullptr, nullptr, MROWS, D_, D_);
        gemm_bt<false, false><<<gg, 256, 0, stream>>>(value, Wv, Vp, nullptr, nullptr, MROWS, D_, D_);
        attn_fwd<<<dim3(S_ / 64, H_, B_), 256, 0, stream>>>(Qp, Kp, Vp, Ap);
        gemm_bt<true, true><<<gg, 256, 0, stream>>>(Ap, Wo, nullptr, out, query, MROWS, D_, D_);
        ln_inplace<<<MROWS, 256, 0, stream>>>(out, gamma, beta);
    }
}

// Round 13
// 112.407 us; speedup vs baseline: 1.5408x; 1.0812x over previous
//
#include <hip/hip_runtime.h>
#include <hip/hip_bf16.h>

// Fused MHA block: y = LN(x @ attn + residual)
// B=4 S=1024 D=1024 H=16 DK=64. fp32 I/O, bf16 MFMA internally.
#define B_ 4
#define S_ 1024
#define D_ 1024
#define H_ 16
#define DK_ 64
#define MROWS (B_*S_)   // 4096

typedef short bf16x8 __attribute__((ext_vector_type(8)));
typedef float f32x4 __attribute__((ext_vector_type(4)));
typedef unsigned short u16;
typedef unsigned u32;
typedef u16 u16x4 __attribute__((ext_vector_type(4)));

__device__ __forceinline__ u16 f2bf(float f) {
    union { float f; unsigned u; } v; v.f = f;
    unsigned u = v.u;
    u += 0x7fff + ((u >> 16) & 1);   // RNE
    return (u16)(u >> 16);
}
__device__ __forceinline__ float bf2f(u16 h) {
    union { unsigned u; float f; } v; v.u = ((unsigned)h) << 16;
    return v.f;
}

__device__ __forceinline__ void gld_lds16(const u16* gp, u16* lp) {
    __builtin_amdgcn_global_load_lds(
        (const __attribute__((address_space(1))) void*)gp,
        (__attribute__((address_space(3))) void*)lp,
        16, 0, 0);
}

// ---------------------------------------------------------------------------
// Pack: fp32 -> bf16 for activations and weights (R6-verified).
// ---------------------------------------------------------------------------
__global__ __launch_bounds__(256) void pack_bf16(
    const float* __restrict__ q, const float* __restrict__ k, const float* __restrict__ v,
    const float* __restrict__ wq, const float* __restrict__ wk,
    const float* __restrict__ wv, const float* __restrict__ wo,
    u16* __restrict__ act_dst, u16* __restrict__ w_dst)
{
    const int NACT = 3 * MROWS * D_;
    const int NW   = 4 * D_ * D_;
    for (int c = blockIdx.x * blockDim.x + threadIdx.x;
         c < (NACT + NW) / 4; c += gridDim.x * blockDim.x) {
        int e = c * 4;
        const float* s; u16* d;
        if (e < NACT) {
            int t = e >> 22;
            int off = e & (4194304 - 1);
            s = (t == 0 ? q : t == 1 ? k : v) + off;
            d = act_dst + e;
        } else {
            int e2 = e - NACT;
            int t = e2 >> 20;
            int off = e2 & (1048576 - 1);
            s = (t == 0 ? wq : t == 1 ? wk : t == 2 ? wv : wo) + off;
            d = w_dst + e2;
        }
        float4 tv = *(const float4*)s;
        u16x4 o; o[0]=f2bf(tv.x); o[1]=f2bf(tv.y); o[2]=f2bf(tv.z); o[3]=f2bf(tv.w);
        *(u16x4*)d = o;
    }
}

// ---------------------------------------------------------------------------
// GEMM v3 (R10-verified): A-reg-preload from LDS + B-double-buffer. Per step:
//   preload A-frags -> sync -> issue stage A(j+1), B(j+1)->buf^1 ->
//   compute (A from regs, B from buf[cur]) -> sync.
// LDS = BM*64*2 + 2*128*64*2 (48KB @BM=128, 40KB @BM=64).
// VT: z==2 stores C transposed (Vt[d][token]).
// EPI_RESID=false, VT=false: plain bf16 C store (used for Wo -> Yb).
// ---------------------------------------------------------------------------
template<int BM, bool EPI_RESID, bool VT>
__global__ __launch_bounds__(256) void gemm_fast(
    const u16* __restrict__ Ab, const u16* __restrict__ Wb,
    u16* __restrict__ Cb, float* __restrict__ Cf, const float* __restrict__ resid)
{
    constexpr int WN = (BM == 128) ? 2 : 4;
    constexpr int WCOLS = 128 / WN;
    constexpr int NR = WCOLS / 16;
    __shared__ u16 ldsA[BM * 64];
    __shared__ u16 ldsB[2][128 * 64];

    const int gx = gridDim.x, gy = gridDim.y, gz = gridDim.z;
    const int nwg = gx * gy * gz;
    const int flat = blockIdx.x + gx * (blockIdx.y + gy * blockIdx.z);
    const int f = (flat & 7) * (nwg >> 3) + (flat >> 3);
    const int bx = f % gx;
    const int rem = f / gx;
    const int by = rem % gy;
    const int z = rem / gy;

    Ab += (size_t)z * MROWS * D_;
    Wb += (size_t)z * D_ * D_;
    const u16* CbT = Cb + (EPI_RESID ? 0 : (size_t)z * MROWS * D_);
    u16* Cbz = (u16*)CbT;

    const int tid = threadIdx.x, lane = tid & 63, wid = tid >> 6;
    const int wr = (BM == 128) ? (wid >> 1) : 0;
    const int wc = (BM == 128) ? (wid & 1) : wid;
    const int m0 = by * BM, n0 = bx * 128;
    const int wbase = wid * 64;

    auto stageA = [&](int it) {
        const int kt = it * 64;
        #pragma unroll
        for (int j = 0; j < BM / 32; ++j) {
            int ch = j * 256 + tid;
            int row = ch >> 3, c8 = (ch & 7) ^ (row & 7);
            gld_lds16(Ab + (size_t)(m0 + row) * 1024 + kt + c8 * 8,
                      &ldsA[(j * 256 + wbase) * 8]);
        }
    };
    auto stageB = [&](int p, int it) {
        const int kt = it * 64;
        #pragma unroll
        for (int j = 0; j < 4; ++j) {
            int ch = j * 256 + tid;
            int row = ch >> 3, c8 = (ch & 7) ^ (row & 7);
            gld_lds16(Wb + (size_t)(n0 + row) * 1024 + kt + c8 * 8,
                      &ldsB[p][(j * 256 + wbase) * 8]);
        }
    };

    f32x4 acc[4][NR] = {};

    stageA(0);
    stageB(0, 0);
    __syncthreads();

    for (int it = 0; it < 16; ++it) {
        const int bcur = it & 1;

        // preload this tile's A fragments into registers
        bf16x8 af[2][4];
        #pragma unroll
        for (int ks = 0; ks < 2; ++ks) {
            const int cb = ks * 32 + (lane >> 4) * 8;
            #pragma unroll
            for (int m = 0; m < 4; ++m) {
                int row = wr * 64 + m * 16 + (lane & 15);
                af[ks][m] = *(const bf16x8*)(&ldsA[row * 64 + (cb ^ ((row & 7) << 3))]);
            }
        }
        __syncthreads();                 // all waves' A reads retired

        if (it < 15) {
            stageA(it + 1);              // overwrite ldsA (safe: frags in regs)
            stageB(bcur ^ 1, it + 1);    // fill other B buffer
        }
        __builtin_amdgcn_sched_barrier(0);   // keep stages ahead of compute

        #pragma unroll
        for (int ks = 0; ks < 2; ++ks) {
            const int cb = ks * 32 + (lane >> 4) * 8;
            bf16x8 bfr[NR];
            #pragma unroll
            for (int n = 0; n < NR; ++n) {
                int row = wc * WCOLS + n * 16 + (lane & 15);
                bfr[n] = *(const bf16x8*)(&ldsB[bcur][row * 64 + (cb ^ ((row & 7) << 3))]);
            }
            #pragma unroll
            for (int m = 0; m < 4; ++m)
                #pragma unroll
                for (int n = 0; n < NR; ++n)
                    acc[m][n] = __builtin_amdgcn_mfma_f32_16x16x32_bf16(
                        af[ks][m], bfr[n], acc[m][n], 0, 0, 0);
        }

        __syncthreads();                 // next tile's A/B landed
    }

    if (VT && z == 2) {
        #pragma unroll
        for (int m = 0; m < 4; ++m)
            #pragma unroll
            for (int n = 0; n < NR; ++n) {
                u16x4 o;
                #pragma unroll
                for (int r = 0; r < 4; ++r) o[r] = f2bf(acc[m][n][r]);
                int grow = m0 + wr * 64 + m * 16 + (lane >> 4) * 4;
                int gcol = n0 + wc * WCOLS + n * 16 + (lane & 15);
                *(u16x4*)(&Cbz[(size_t)gcol * MROWS + grow]) = o;
            }
    } else {
        #pragma unroll
        for (int m = 0; m < 4; ++m)
            #pragma unroll
            for (int n = 0; n < NR; ++n)
                #pragma unroll
                for (int r = 0; r < 4; ++r) {
                    int grow = m0 + wr * 64 + m * 16 + (lane >> 4) * 4 + r;
                    int gcol = n0 + wc * WCOLS + n * 16 + (lane & 15);
                    if (EPI_RESID)
                        Cf[(size_t)grow * 1024 + gcol] = acc[m][n][r] + resid[(size_t)grow * 1024 + gcol];
                    else
                        Cbz[(size_t)grow * 1024 + gcol] = f2bf(acc[m][n][r]);
                }
    }
}

// ---------------------------------------------------------------------------
// Fallback GEMM (round-1 path), unchanged.
// ---------------------------------------------------------------------------
template<bool A_BF16, bool EPI_RESID>
__global__ __launch_bounds__(256) void gemm_bt(
    const void* __restrict__ Av, const float* __restrict__ Bw,
    u16* __restrict__ Cb, float* __restrict__ Cf,
    const float* __restrict__ resid, int M, int N, int K)
{
    __shared__ u16 lds[2][128 * 64];
    const int tid  = threadIdx.x;
    const int lane = tid & 63;
    const int wid  = tid >> 6;
    const int wr = wid >> 1, wc = wid & 1;
    const int m0 = blockIdx.y * 128, n0 = blockIdx.x * 128;

    f32x4 acc[4][4] = {};

    for (int kt = 0; kt < K; kt += 64) {
        #pragma unroll
        for (int j = 0; j < 8; ++j) {
            int idx4 = tid + 256 * j;
            int r = idx4 >> 4;
            int c = (idx4 & 15) * 4;
            u16x4 aw, bw;
            if (A_BF16) {
                const u16* Ab2 = (const u16*)Av;
                aw = *(const u16x4*)(Ab2 + (size_t)(m0 + r) * K + kt + c);
            } else {
                const float* Af = (const float*)Av;
                float4 t = *(const float4*)(Af + (size_t)(m0 + r) * K + kt + c);
                aw[0] = f2bf(t.x); aw[1] = f2bf(t.y); aw[2] = f2bf(t.z); aw[3] = f2bf(t.w);
            }
            {
                float4 t = *(const float4*)(Bw + (size_t)(n0 + r) * K + kt + c);
                bw[0] = f2bf(t.x); bw[1] = f2bf(t.y); bw[2] = f2bf(t.z); bw[3] = f2bf(t.w);
            }
            int sa = r * 64 + (c ^ ((r & 7) << 3));
            *(u16x4*)(&lds[0][sa]) = aw;
            *(u16x4*)(&lds[1][sa]) = bw;
        }
        __syncthreads();
        #pragma unroll
        for (int ks = 0; ks < 2; ++ks) {
            const int cb = ks * 32 + (lane >> 4) * 8;
            bf16x8 af[4], bfr[4];
            #pragma unroll
            for (int m = 0; m < 4; ++m) {
                int row = wr * 64 + m * 16 + (lane & 15);
                af[m] = *(const bf16x8*)(&lds[0][row * 64 + (cb ^ ((row & 7) << 3))]);
            }
            #pragma unroll
            for (int n = 0; n < 4; ++n) {
                int row = wc * 64 + n * 16 + (lane & 15);
                bfr[n] = *(const bf16x8*)(&lds[1][row * 64 + (cb ^ ((row & 7) << 3))]);
            }
            #pragma unroll
            for (int m = 0; m < 4; ++m)
                #pragma unroll
                for (int n = 0; n < 4; ++n)
                    acc[m][n] = __builtin_amdgcn_mfma_f32_16x16x32_bf16(
                        af[m], bfr[n], acc[m][n], 0, 0, 0);
        }
        __syncthreads();
    }

    #pragma unroll
    for (int m = 0; m < 4; ++m)
        #pragma unroll
        for (int n = 0; n < 4; ++n)
            #pragma unroll
            for (int r = 0; r < 4; ++r) {
                int grow = m0 + wr * 64 + m * 16 + (lane >> 4) * 4 + r;
                int gcol = n0 + wc * 64 + n * 16 + (lane & 15);
                float v = acc[m][n][r];
                if (EPI_RESID)
                    Cf[(size_t)grow * N + gcol] = v + resid[(size_t)grow * N + gcol];
                else
                    Cb[(size_t)grow * N + gcol] = f2bf(v);
            }
}

// ---------------------------------------------------------------------------
// Flash attention v6 (R9-verified): swapped QK^T, in-lane softmax,
// wave-private P, Vt-from-global, split-stage pipeline, Q-in-reg, defer-max.
// ---------------------------------------------------------------------------
__global__ __launch_bounds__(512, 4) void attn_fwd6(
    const u16* __restrict__ Qg, const u16* __restrict__ Kg,
    const u16* __restrict__ Vt, u16* __restrict__ Og)
{
    __shared__ u16 ks2[64 * 64];
    __shared__ u16 vsT[64 * 64];
    __shared__ u16 ps[128 * 64];

    const int tid = threadIdx.x, lane = tid & 63, w = tid >> 6;
    const int g = lane >> 4, ql = lane & 15;

    const int bid = blockIdx.x;
    const int f = (bid & 7) * 64 + (bid >> 3);
    const int qt = f & 7, h = (f >> 3) & 15, b = f >> 7;
    const int q0 = qt * 128;
    const size_t rbase = (size_t)b * S_;
    const int cb0 = h * DK_;

    bf16x8 qb[2];
    {
        const u16* qp = Qg + (rbase + q0 + w * 16 + ql) * D_ + cb0 + 8 * g;
        qb[0] = *(const bf16x8*)(qp);
        qb[1] = *(const bf16x8*)(qp + 32);
    }

    auto stage_k = [&](int kv0) {
        int row = tid >> 3, c8 = (tid & 7) ^ (row & 7);
        gld_lds16(Kg + (rbase + kv0 + row) * D_ + cb0 + c8 * 8, &ks2[w * 512]);
    };
    auto stage_v = [&](int kv0) {
        int row = tid >> 3, c8 = (tid & 7) ^ (row & 7);
        gld_lds16(Vt + (size_t)(cb0 + row) * MROWS + rbase + kv0 + c8 * 8, &vsT[w * 512]);
    };

    stage_k(0);
    stage_v(0);
    __syncthreads();

    float mrow = -1e30f, lrow = 0.f;
    f32x4 xacc[4] = {};

    for (int jt = 0; jt < 16; ++jt) {
        f32x4 sacc[4] = {};
        __builtin_amdgcn_s_setprio(1);
        #pragma unroll
        for (int ks = 0; ks < 2; ++ks) {
            #pragma unroll
            for (int n = 0; n < 4; ++n) {
                int krow = n * 16 + ql;
                int c = 32 * ks + 8 * g;
                bf16x8 kf = *(const bf16x8*)(&ks2[krow * 64 + (c ^ ((krow & 7) << 3))]);
                sacc[n] = __builtin_amdgcn_mfma_f32_16x16x32_bf16(kf, qb[ks], sacc[n], 0, 0, 0);
            }
        }
        __builtin_amdgcn_s_setprio(0);

        __syncthreads();
        if (jt < 15) stage_k((jt + 1) * 64);

        float mt = sacc[0][0];
        #pragma unroll
        for (int n = 0; n < 4; ++n)
            #pragma unroll
            for (int r = 0; r < 4; ++r) mt = fmaxf(mt, sacc[n][r]);
        mt = fmaxf(mt, __shfl_xor(mt, 16));
        mt = fmaxf(mt, __shfl_xor(mt, 32));
        if (!__all(mt * 0.125f - mrow <= 8.f)) {
            float mnew = fmaxf(mrow, mt * 0.125f);
            float alpha = __expf(mrow - mnew);
            mrow = mnew;
            lrow *= alpha;
            #pragma unroll
            for (int r = 0; r < 4; ++r) {
                float a_r = __shfl(alpha, 4 * g + r);
                #pragma unroll
                for (int n2 = 0; n2 < 4; ++n2) xacc[n2][r] *= a_r;
            }
        }
        float rsum = 0.f;
        u16 pb[16];
        #pragma unroll
        for (int n = 0; n < 4; ++n)
            #pragma unroll
            for (int r = 0; r < 4; ++r) {
                float p = __expf(sacc[n][r] * 0.125f - mrow);
                rsum += p;
                pb[n * 4 + r] = f2bf(p);
            }
        rsum += __shfl_xor(rsum, 16);
        rsum += __shfl_xor(rsum, 32);
        lrow += rsum;

        {
            const int q = w * 16 + ql;
            #pragma unroll
            for (int n = 0; n < 4; ++n) {
                int c = 16 * n + 4 * g;
                *(u16x4*)(&ps[q * 64 + (c ^ ((q & 7) << 3))]) = *(const u16x4*)(&pb[n * 4]);
            }
        }
        asm volatile("s_waitcnt lgkmcnt(0)" ::: "memory");
        __builtin_amdgcn_sched_barrier(0);

        bf16x8 pa[2];
        {
            const int q = w * 16 + ql;
            #pragma unroll
            for (int ks = 0; ks < 2; ++ks) {
                int c = 32 * ks + 8 * g;
                pa[ks] = *(const bf16x8*)(&ps[q * 64 + (c ^ ((q & 7) << 3))]);
            }
        }

        __builtin_amdgcn_s_setprio(1);
        #pragma unroll
        for (int ks = 0; ks < 2; ++ks)
            #pragma unroll
            for (int n2 = 0; n2 < 4; ++n2) {
                int vrow = n2 * 16 + ql;
                int c2 = 32 * ks + 8 * g;
                bf16x8 bv = *(const bf16x8*)(&vsT[vrow * 64 + (c2 ^ ((vrow & 7) << 3))]);
                xacc[n2] = __builtin_amdgcn_mfma_f32_16x16x32_bf16(pa[ks], bv, xacc[n2], 0, 0, 0);
            }
        __builtin_amdgcn_s_setprio(0);

        __syncthreads();
        if (jt < 15) stage_v((jt + 1) * 64);
    }

    float linv[4];
    #pragma unroll
    for (int r = 0; r < 4; ++r) linv[r] = 1.f / __shfl(lrow, 4 * g + r);
    #pragma unroll
    for (int n2 = 0; n2 < 4; ++n2)
        #pragma unroll
        for (int r = 0; r < 4; ++r) {
            int qrow = q0 + w * 16 + 4 * g + r;
            int col = cb0 + n2 * 16 + ql;
            Og[(rbase + qrow) * D_ + col] = f2bf(xacc[n2][r] * linv[r]);
        }
}

// ---------------------------------------------------------------------------
// Flash attention (R2-verified version) for the fallback path.
// ---------------------------------------------------------------------------
__global__ __launch_bounds__(256) void attn_fwd(
    const u16* __restrict__ Qg, const u16* __restrict__ Kg,
    const u16* __restrict__ Vg, u16* __restrict__ Og)
{
    __shared__ u16 qs[64 * 64], ks2[64 * 64], vt[64 * 64], ps[64 * 64];
    const int tid = threadIdx.x, lane = tid & 63, w = tid >> 6;
    const int b = blockIdx.z, h = blockIdx.y, q0 = blockIdx.x * 64;
    const size_t rbase = (size_t)b * S_;
    const int cb0 = h * DK_;

    #pragma unroll
    for (int j = 0; j < 4; ++j) {
        int idx4 = tid + 256 * j;
        int r = idx4 >> 4, c = (idx4 & 15) * 4;
        u16x4 t = *(const u16x4*)(Qg + (rbase + q0 + r) * D_ + cb0 + c);
        *(u16x4*)(&qs[r * 64 + (c ^ ((r & 7) << 3))]) = t;
    }

    float mrow[4], lrow[4];
    f32x4 xacc[4] = {};
    #pragma unroll
    for (int r = 0; r < 4; ++r) { mrow[r] = -1e30f; lrow[r] = 0.f; }

    for (int jt = 0; jt < 16; ++jt) {
        const int kv0 = jt * 64;
        __syncthreads();
        #pragma unroll
        for (int j = 0; j < 4; ++j) {
            int idx4 = tid + 256 * j;
            int r = idx4 >> 4, c = (idx4 & 15) * 4;
            u16x4 t = *(const u16x4*)(Kg + (rbase + kv0 + r) * D_ + cb0 + c);
            *(u16x4*)(&ks2[r * 64 + (c ^ ((r & 7) << 3))]) = t;
            u16x4 tv = *(const u16x4*)(Vg + (rbase + kv0 + r) * D_ + cb0 + c);
            #pragma unroll
            for (int jj = 0; jj < 4; ++jj) {
                int d = c + jj;
                vt[d * 64 + (r ^ ((d & 7) << 3))] = tv[jj];
            }
        }
        __syncthreads();

        f32x4 sacc[4] = {};
        #pragma unroll
        for (int ks = 0; ks < 2; ++ks) {
            const int cb = ks * 32 + (lane >> 4) * 8;
            int qrow = w * 16 + (lane & 15);
            bf16x8 aq = *(const bf16x8*)(&qs[qrow * 64 + (cb ^ ((qrow & 7) << 3))]);
            #pragma unroll
            for (int n = 0; n < 4; ++n) {
                int krow = n * 16 + (lane & 15);
                bf16x8 bk = *(const bf16x8*)(&ks2[krow * 64 + (cb ^ ((krow & 7) << 3))]);
                sacc[n] = __builtin_amdgcn_mfma_f32_16x16x32_bf16(aq, bk, sacc[n], 0, 0, 0);
            }
        }

        #pragma unroll
        for (int r = 0; r < 4; ++r) {
            float mx = fmaxf(fmaxf(sacc[0][r], sacc[1][r]),
                             fmaxf(sacc[2][r], sacc[3][r]));
            mx = fmaxf(mx, __shfl_xor(mx, 1));
            mx = fmaxf(mx, __shfl_xor(mx, 2));
            mx = fmaxf(mx, __shfl_xor(mx, 4));
            mx = fmaxf(mx, __shfl_xor(mx, 8));
            float mnew = fmaxf(mrow[r], mx * 0.125f);
            float alpha = __expf(mrow[r] - mnew);
            float p[4], rsum = 0.f;
            #pragma unroll
            for (int n = 0; n < 4; ++n) { p[n] = __expf(sacc[n][r] * 0.125f - mnew); rsum += p[n]; }
            rsum += __shfl_xor(rsum, 1);
            rsum += __shfl_xor(rsum, 2);
            rsum += __shfl_xor(rsum, 4);
            rsum += __shfl_xor(rsum, 8);
            lrow[r] = lrow[r] * alpha + rsum;
            mrow[r] = mnew;
            int qrow = w * 16 + (lane >> 4) * 4 + r;
            #pragma unroll
            for (int n = 0; n < 4; ++n) {
                xacc[n][r] *= alpha;
                int col = n * 16 + (lane & 15);
                ps[qrow * 64 + (col ^ ((qrow & 7) << 3))] = f2bf(p[n]);
            }
        }
        __syncthreads();

        #pragma unroll
        for (int ks = 0; ks < 2; ++ks) {
            const int cb = ks * 32 + (lane >> 4) * 8;
            int prow = w * 16 + (lane & 15);
            bf16x8 ap = *(const bf16x8*)(&ps[prow * 64 + (cb ^ ((prow & 7) << 3))]);
            #pragma unroll
            for (int n = 0; n < 4; ++n) {
                int vrow = n * 16 + (lane & 15);
                bf16x8 bv = *(const bf16x8*)(&vt[vrow * 64 + (cb ^ ((vrow & 7) << 3))]);
                xacc[n] = __builtin_amdgcn_mfma_f32_16x16x32_bf16(ap, bv, xacc[n], 0, 0, 0);
            }
        }
    }

    #pragma unroll
    for (int n = 0; n < 4; ++n)
        #pragma unroll
        for (int r = 0; r < 4; ++r) {
            int qrow = q0 + w * 16 + (lane >> 4) * 4 + r;
            int col = cb0 + n * 16 + (lane & 15);
            Og[(rbase + qrow) * D_ + col] = f2bf(xacc[n][r] / lrow[r]);
        }
}

// ---------------------------------------------------------------------------
// LN fused: y = LN(bf16(Y) + resid) * gamma + beta, fp32 out. One block/row.
// ---------------------------------------------------------------------------
__global__ __launch_bounds__(256) void ln_fused(
    const u16* __restrict__ Yb, const float* __restrict__ resid,
    const float* __restrict__ g, const float* __restrict__ bt,
    float* __restrict__ out)
{
    __shared__ float red[2][4];
    const int row = blockIdx.x, tid = threadIdx.x;
    u16x4 yv = *(const u16x4*)(Yb + (size_t)row * D_ + tid * 4);
    float4 rv = *(const float4*)(resid + (size_t)row * D_ + tid * 4);
    float x0 = bf2f(yv[0]) + rv.x;
    float x1 = bf2f(yv[1]) + rv.y;
    float x2 = bf2f(yv[2]) + rv.z;
    float x3 = bf2f(yv[3]) + rv.w;
    float s = x0 + x1 + x2 + x3;
    float q = x0 * x0 + x1 * x1 + x2 * x2 + x3 * x3;
    #pragma unroll
    for (int m = 1; m < 64; m <<= 1) { s += __shfl_xor(s, m); q += __shfl_xor(q, m); }
    const int w = tid >> 6, lane = tid & 63;
    if (lane == 0) { red[0][w] = s; red[1][w] = q; }
    __syncthreads();
    s = red[0][0] + red[0][1] + red[0][2] + red[0][3];
    q = red[1][0] + red[1][1] + red[1][2] + red[1][3];
    float mu = s * (1.f / 1024.f);
    float var = q * (1.f / 1024.f) - mu * mu;
    float rstd = rsqrtf(var + 1e-6f);
    float4 gv = *(const float4*)(g + tid * 4);
    float4 bv = *(const float4*)(bt + tid * 4);
    float4 o;
    o.x = (x0 - mu) * rstd * gv.x + bv.x;
    o.y = (x1 - mu) * rstd * gv.y + bv.y;
    o.z = (x2 - mu) * rstd * gv.z + bv.z;
    o.w = (x3 - mu) * rstd * gv.w + bv.w;
    *(float4*)(out + (size_t)row * D_ + tid * 4) = o;
}

// ---------------------------------------------------------------------------
// LayerNorm in-place on fp32 [4096][1024] (fallback path).
// ---------------------------------------------------------------------------
__global__ __launch_bounds__(256) void ln_inplace(
    float* __restrict__ Y, const float* __restrict__ g, const float* __restrict__ bt)
{
    __shared__ float red[2][4];
    const int row = blockIdx.x, tid = threadIdx.x;
    float4 v = *(const float4*)(Y + (size_t)row * D_ + tid * 4);
    float s = v.x + v.y + v.z + v.w;
    float q = v.x * v.x + v.y * v.y + v.z * v.z + v.w * v.w;
    #pragma unroll
    for (int m = 1; m < 64; m <<= 1) { s += __shfl_xor(s, m); q += __shfl_xor(q, m); }
    const int w = tid >> 6, lane = tid & 63;
    if (lane == 0) { red[0][w] = s; red[1][w] = q; }
    __syncthreads();
    s = red[0][0] + red[0][1] + red[0][2] + red[0][3];
    q = red[1][0] + red[1][1] + red[1][2] + red[1][3];
    float mu = s * (1.f / 1024.f);
    float var = q * (1.f / 1024.f) - mu * mu;
    float rstd = rsqrtf(var + 1e-6f);
    float4 gv = *(const float4*)(g + tid * 4);
    float4 bv = *(const float4*)(bt + tid * 4);
    v.x = (v.x - mu) * rstd * gv.x + bv.x;
    v.y = (v.y - mu) * rstd * gv.y + bv.y;
    v.z = (v.z - mu) * rstd * gv.z + bv.z;
    v.w = (v.w - mu) * rstd * gv.w + bv.w;
    *(float4*)(Y + (size_t)row * D_ + tid * 4) = v;
}

extern "C" void kernel_launch(void* const* d_in, const int* in_sizes, int n_in,
                              void* d_out, int out_size, void* d_ws, size_t ws_size,
                              hipStream_t stream)
{
    const float* query = (const float*)d_in[0];
    const float* key   = (const float*)d_in[1];
    const float* value = (const float*)d_in[2];
    const float* Wq    = (const float*)d_in[3];
    const float* Wk    = (const float*)d_in[4];
    const float* Wv    = (const float*)d_in[5];
    const float* Wo    = (const float*)d_in[6];
    const float* gamma = (const float*)d_in[7];
    const float* beta  = (const float*)d_in[8];
    float* out = (float*)d_out;

    const size_t ACT = (size_t)MROWS * D_;
    const size_t WSZ = (size_t)D_ * D_;
    const size_t NEED = (3 * ACT + 4 * WSZ + 3 * ACT) * 2;   // 58,720,256 B

    if (ws_size >= NEED) {
        u16* actb = (u16*)d_ws;
        u16* wb   = actb + 3 * ACT;
        u16* pb   = wb + 4 * WSZ;      // Qp | Kp | Vt (transposed)
        u16* Ap   = actb;               // alias: q-packed dead after QKV gemm
        u16* Yb   = actb + ACT;         // alias: k-packed dead after QKV gemm

        pack_bf16<<<2048, 256, 0, stream>>>(query, key, value, Wq, Wk, Wv, Wo, actb, wb);
        gemm_fast<128, false, true><<<dim3(8, 32, 3), 256, 0, stream>>>(actb, wb, pb, nullptr, nullptr);
        attn_fwd6<<<512, 512, 0, stream>>>(pb, pb + ACT, pb + 2 * ACT, Ap);
        gemm_fast<64, false, false><<<dim3(8, 64, 1), 256, 0, stream>>>(Ap, wb + 3 * WSZ, Yb, nullptr, nullptr);
        ln_fused<<<MROWS, 256, 0, stream>>>(Yb, query, gamma, beta, out);
    } else {
        u16* Qp = (u16*)d_ws;
        u16* Kp = Qp + ACT;
        u16* Vp = Kp + ACT;
        u16* Ap = Vp + ACT;
        dim3 gg(D_ / 128, MROWS / 128);
        gemm_bt<false, false><<<gg, 256, 0, stream>>>(query, Wq, Qp, nullptr, nullptr, MROWS, D_, D_);
        gemm_bt<false, false><<<gg, 256, 0, stream>>>(key,   Wk, Kp, nullptr, nullptr, MROWS, D_, D_);
        gemm_bt<false, false><<<gg, 256, 0, stream>>>(value, Wv, Vp, nullptr, nullptr, MROWS, D_, D_);
        attn_fwd<<<dim3(S_ / 64, H_, B_), 256, 0, stream>>>(Qp, Kp, Vp, Ap);
        gemm_bt<true, true><<<gg, 256, 0, stream>>>(Ap, Wo, nullptr, out, query, MROWS, D_, D_);
        ln_inplace<<<MROWS, 256, 0, stream>>>(out, gamma, beta);
    }
}

// Round 14
// 111.924 us; speedup vs baseline: 1.5475x; 1.0043x over previous
//
#include <hip/hip_runtime.h>
#include <hip/hip_bf16.h>

// Fused MHA block: y = LN(x @ attn + residual)
// B=4 S=1024 D=1024 H=16 DK=64. fp32 I/O, bf16 MFMA internally.
#define B_ 4
#define S_ 1024
#define D_ 1024
#define H_ 16
#define DK_ 64
#define MROWS (B_*S_)   // 4096

typedef short bf16x8 __attribute__((ext_vector_type(8)));
typedef float f32x4 __attribute__((ext_vector_type(4)));
typedef unsigned short u16;
typedef unsigned u32;
typedef u16 u16x4 __attribute__((ext_vector_type(4)));

__device__ __forceinline__ u16 f2bf(float f) {
    union { float f; unsigned u; } v; v.f = f;
    unsigned u = v.u;
    u += 0x7fff + ((u >> 16) & 1);   // RNE
    return (u16)(u >> 16);
}
__device__ __forceinline__ float bf2f(u16 h) {
    union { unsigned u; float f; } v; v.u = ((unsigned)h) << 16;
    return v.f;
}

__device__ __forceinline__ void gld_lds16(const u16* gp, u16* lp) {
    __builtin_amdgcn_global_load_lds(
        (const __attribute__((address_space(1))) void*)gp,
        (__attribute__((address_space(3))) void*)lp,
        16, 0, 0);
}

// ---------------------------------------------------------------------------
// Pack: fp32 -> bf16 for activations and weights (R6-verified).
// ---------------------------------------------------------------------------
__global__ __launch_bounds__(256) void pack_bf16(
    const float* __restrict__ q, const float* __restrict__ k, const float* __restrict__ v,
    const float* __restrict__ wq, const float* __restrict__ wk,
    const float* __restrict__ wv, const float* __restrict__ wo,
    u16* __restrict__ act_dst, u16* __restrict__ w_dst)
{
    const int NACT = 3 * MROWS * D_;
    const int NW   = 4 * D_ * D_;
    for (int c = blockIdx.x * blockDim.x + threadIdx.x;
         c < (NACT + NW) / 4; c += gridDim.x * blockDim.x) {
        int e = c * 4;
        const float* s; u16* d;
        if (e < NACT) {
            int t = e >> 22;
            int off = e & (4194304 - 1);
            s = (t == 0 ? q : t == 1 ? k : v) + off;
            d = act_dst + e;
        } else {
            int e2 = e - NACT;
            int t = e2 >> 20;
            int off = e2 & (1048576 - 1);
            s = (t == 0 ? wq : t == 1 ? wk : t == 2 ? wv : wo) + off;
            d = w_dst + e2;
        }
        float4 tv = *(const float4*)s;
        u16x4 o; o[0]=f2bf(tv.x); o[1]=f2bf(tv.y); o[2]=f2bf(tv.z); o[3]=f2bf(tv.w);
        *(u16x4*)d = o;
    }
}

// ---------------------------------------------------------------------------
// GEMM v3 (R10-verified): A-reg-preload from LDS + B-double-buffer. Per step:
//   preload A-frags -> sync -> issue stage A(j+1), B(j+1)->buf^1 ->
//   compute (A from regs, B from buf[cur]) -> sync.
// LDS = BM*64*2 + 2*128*64*2 (48KB @BM=128, 40KB @BM=64).
// VT: z==2 stores C transposed (Vt[d][token]).
// EPI_RESID=false, VT=false: plain bf16 C store (used for Wo -> Yb).
// ---------------------------------------------------------------------------
template<int BM, bool EPI_RESID, bool VT>
__global__ __launch_bounds__(256) void gemm_fast(
    const u16* __restrict__ Ab, const u16* __restrict__ Wb,
    u16* __restrict__ Cb, float* __restrict__ Cf, const float* __restrict__ resid)
{
    constexpr int WN = (BM == 128) ? 2 : 4;
    constexpr int WCOLS = 128 / WN;
    constexpr int NR = WCOLS / 16;
    __shared__ u16 ldsA[BM * 64];
    __shared__ u16 ldsB[2][128 * 64];

    const int gx = gridDim.x, gy = gridDim.y, gz = gridDim.z;
    const int nwg = gx * gy * gz;
    const int flat = blockIdx.x + gx * (blockIdx.y + gy * blockIdx.z);
    const int f = (flat & 7) * (nwg >> 3) + (flat >> 3);
    const int bx = f % gx;
    const int rem = f / gx;
    const int by = rem % gy;
    const int z = rem / gy;

    Ab += (size_t)z * MROWS * D_;
    Wb += (size_t)z * D_ * D_;
    const u16* CbT = Cb + (EPI_RESID ? 0 : (size_t)z * MROWS * D_);
    u16* Cbz = (u16*)CbT;

    const int tid = threadIdx.x, lane = tid & 63, wid = tid >> 6;
    const int wr = (BM == 128) ? (wid >> 1) : 0;
    const int wc = (BM == 128) ? (wid & 1) : wid;
    const int m0 = by * BM, n0 = bx * 128;
    const int wbase = wid * 64;

    auto stageA = [&](int it) {
        const int kt = it * 64;
        #pragma unroll
        for (int j = 0; j < BM / 32; ++j) {
            int ch = j * 256 + tid;
            int row = ch >> 3, c8 = (ch & 7) ^ (row & 7);
            gld_lds16(Ab + (size_t)(m0 + row) * 1024 + kt + c8 * 8,
                      &ldsA[(j * 256 + wbase) * 8]);
        }
    };
    auto stageB = [&](int p, int it) {
        const int kt = it * 64;
        #pragma unroll
        for (int j = 0; j < 4; ++j) {
            int ch = j * 256 + tid;
            int row = ch >> 3, c8 = (ch & 7) ^ (row & 7);
            gld_lds16(Wb + (size_t)(n0 + row) * 1024 + kt + c8 * 8,
                      &ldsB[p][(j * 256 + wbase) * 8]);
        }
    };

    f32x4 acc[4][NR] = {};

    stageA(0);
    stageB(0, 0);
    __syncthreads();

    for (int it = 0; it < 16; ++it) {
        const int bcur = it & 1;

        // preload this tile's A fragments into registers
        bf16x8 af[2][4];
        #pragma unroll
        for (int ks = 0; ks < 2; ++ks) {
            const int cb = ks * 32 + (lane >> 4) * 8;
            #pragma unroll
            for (int m = 0; m < 4; ++m) {
                int row = wr * 64 + m * 16 + (lane & 15);
                af[ks][m] = *(const bf16x8*)(&ldsA[row * 64 + (cb ^ ((row & 7) << 3))]);
            }
        }
        __syncthreads();                 // all waves' A reads retired

        if (it < 15) {
            stageA(it + 1);              // overwrite ldsA (safe: frags in regs)
            stageB(bcur ^ 1, it + 1);    // fill other B buffer
        }
        __builtin_amdgcn_sched_barrier(0);   // keep stages ahead of compute

        #pragma unroll
        for (int ks = 0; ks < 2; ++ks) {
            const int cb = ks * 32 + (lane >> 4) * 8;
            bf16x8 bfr[NR];
            #pragma unroll
            for (int n = 0; n < NR; ++n) {
                int row = wc * WCOLS + n * 16 + (lane & 15);
                bfr[n] = *(const bf16x8*)(&ldsB[bcur][row * 64 + (cb ^ ((row & 7) << 3))]);
            }
            #pragma unroll
            for (int m = 0; m < 4; ++m)
                #pragma unroll
                for (int n = 0; n < NR; ++n)
                    acc[m][n] = __builtin_amdgcn_mfma_f32_16x16x32_bf16(
                        af[ks][m], bfr[n], acc[m][n], 0, 0, 0);
        }

        __syncthreads();                 // next tile's A/B landed
    }

    if (VT && z == 2) {
        #pragma unroll
        for (int m = 0; m < 4; ++m)
            #pragma unroll
            for (int n = 0; n < NR; ++n) {
                u16x4 o;
                #pragma unroll
                for (int r = 0; r < 4; ++r) o[r] = f2bf(acc[m][n][r]);
                int grow = m0 + wr * 64 + m * 16 + (lane >> 4) * 4;
                int gcol = n0 + wc * WCOLS + n * 16 + (lane & 15);
                *(u16x4*)(&Cbz[(size_t)gcol * MROWS + grow]) = o;
            }
    } else {
        #pragma unroll
        for (int m = 0; m < 4; ++m)
            #pragma unroll
            for (int n = 0; n < NR; ++n)
                #pragma unroll
                for (int r = 0; r < 4; ++r) {
                    int grow = m0 + wr * 64 + m * 16 + (lane >> 4) * 4 + r;
                    int gcol = n0 + wc * WCOLS + n * 16 + (lane & 15);
                    if (EPI_RESID)
                        Cf[(size_t)grow * 1024 + gcol] = acc[m][n][r] + resid[(size_t)grow * 1024 + gcol];
                    else
                        Cbz[(size_t)grow * 1024 + gcol] = f2bf(acc[m][n][r]);
                }
    }
}

// ---------------------------------------------------------------------------
// Fallback GEMM (round-1 path), unchanged.
// ---------------------------------------------------------------------------
template<bool A_BF16, bool EPI_RESID>
__global__ __launch_bounds__(256) void gemm_bt(
    const void* __restrict__ Av, const float* __restrict__ Bw,
    u16* __restrict__ Cb, float* __restrict__ Cf,
    const float* __restrict__ resid, int M, int N, int K)
{
    __shared__ u16 lds[2][128 * 64];
    const int tid  = threadIdx.x;
    const int lane = tid & 63;
    const int wid  = tid >> 6;
    const int wr = wid >> 1, wc = wid & 1;
    const int m0 = blockIdx.y * 128, n0 = blockIdx.x * 128;

    f32x4 acc[4][4] = {};

    for (int kt = 0; kt < K; kt += 64) {
        #pragma unroll
        for (int j = 0; j < 8; ++j) {
            int idx4 = tid + 256 * j;
            int r = idx4 >> 4;
            int c = (idx4 & 15) * 4;
            u16x4 aw, bw;
            if (A_BF16) {
                const u16* Ab2 = (const u16*)Av;
                aw = *(const u16x4*)(Ab2 + (size_t)(m0 + r) * K + kt + c);
            } else {
                const float* Af = (const float*)Av;
                float4 t = *(const float4*)(Af + (size_t)(m0 + r) * K + kt + c);
                aw[0] = f2bf(t.x); aw[1] = f2bf(t.y); aw[2] = f2bf(t.z); aw[3] = f2bf(t.w);
            }
            {
                float4 t = *(const float4*)(Bw + (size_t)(n0 + r) * K + kt + c);
                bw[0] = f2bf(t.x); bw[1] = f2bf(t.y); bw[2] = f2bf(t.z); bw[3] = f2bf(t.w);
            }
            int sa = r * 64 + (c ^ ((r & 7) << 3));
            *(u16x4*)(&lds[0][sa]) = aw;
            *(u16x4*)(&lds[1][sa]) = bw;
        }
        __syncthreads();
        #pragma unroll
        for (int ks = 0; ks < 2; ++ks) {
            const int cb = ks * 32 + (lane >> 4) * 8;
            bf16x8 af[4], bfr[4];
            #pragma unroll
            for (int m = 0; m < 4; ++m) {
                int row = wr * 64 + m * 16 + (lane & 15);
                af[m] = *(const bf16x8*)(&lds[0][row * 64 + (cb ^ ((row & 7) << 3))]);
            }
            #pragma unroll
            for (int n = 0; n < 4; ++n) {
                int row = wc * 64 + n * 16 + (lane & 15);
                bfr[n] = *(const bf16x8*)(&lds[1][row * 64 + (cb ^ ((row & 7) << 3))]);
            }
            #pragma unroll
            for (int m = 0; m < 4; ++m)
                #pragma unroll
                for (int n = 0; n < 4; ++n)
                    acc[m][n] = __builtin_amdgcn_mfma_f32_16x16x32_bf16(
                        af[m], bfr[n], acc[m][n], 0, 0, 0);
        }
        __syncthreads();
    }

    #pragma unroll
    for (int m = 0; m < 4; ++m)
        #pragma unroll
        for (int n = 0; n < 4; ++n)
            #pragma unroll
            for (int r = 0; r < 4; ++r) {
                int grow = m0 + wr * 64 + m * 16 + (lane >> 4) * 4 + r;
                int gcol = n0 + wc * 64 + n * 16 + (lane & 15);
                float v = acc[m][n][r];
                if (EPI_RESID)
                    Cf[(size_t)grow * N + gcol] = v + resid[(size_t)grow * N + gcol];
                else
                    Cb[(size_t)grow * N + gcol] = f2bf(v);
            }
}

// ---------------------------------------------------------------------------
// Flash attention v6 (R9-verified): swapped QK^T, in-lane softmax,
// wave-private P, Vt-from-global, split-stage pipeline, Q-in-reg, defer-max.
// ---------------------------------------------------------------------------
__global__ __launch_bounds__(512, 4) void attn_fwd6(
    const u16* __restrict__ Qg, const u16* __restrict__ Kg,
    const u16* __restrict__ Vt, u16* __restrict__ Og)
{
    __shared__ u16 ks2[64 * 64];
    __shared__ u16 vsT[64 * 64];
    __shared__ u16 ps[128 * 64];

    const int tid = threadIdx.x, lane = tid & 63, w = tid >> 6;
    const int g = lane >> 4, ql = lane & 15;

    const int bid = blockIdx.x;
    const int f = (bid & 7) * 64 + (bid >> 3);
    const int qt = f & 7, h = (f >> 3) & 15, b = f >> 7;
    const int q0 = qt * 128;
    const size_t rbase = (size_t)b * S_;
    const int cb0 = h * DK_;

    bf16x8 qb[2];
    {
        const u16* qp = Qg + (rbase + q0 + w * 16 + ql) * D_ + cb0 + 8 * g;
        qb[0] = *(const bf16x8*)(qp);
        qb[1] = *(const bf16x8*)(qp + 32);
    }

    auto stage_k = [&](int kv0) {
        int row = tid >> 3, c8 = (tid & 7) ^ (row & 7);
        gld_lds16(Kg + (rbase + kv0 + row) * D_ + cb0 + c8 * 8, &ks2[w * 512]);
    };
    auto stage_v = [&](int kv0) {
        int row = tid >> 3, c8 = (tid & 7) ^ (row & 7);
        gld_lds16(Vt + (size_t)(cb0 + row) * MROWS + rbase + kv0 + c8 * 8, &vsT[w * 512]);
    };

    stage_k(0);
    stage_v(0);
    __syncthreads();

    float mrow = -1e30f, lrow = 0.f;
    f32x4 xacc[4] = {};

    for (int jt = 0; jt < 16; ++jt) {
        f32x4 sacc[4] = {};
        __builtin_amdgcn_s_setprio(1);
        #pragma unroll
        for (int ks = 0; ks < 2; ++ks) {
            #pragma unroll
            for (int n = 0; n < 4; ++n) {
                int krow = n * 16 + ql;
                int c = 32 * ks + 8 * g;
                bf16x8 kf = *(const bf16x8*)(&ks2[krow * 64 + (c ^ ((krow & 7) << 3))]);
                sacc[n] = __builtin_amdgcn_mfma_f32_16x16x32_bf16(kf, qb[ks], sacc[n], 0, 0, 0);
            }
        }
        __builtin_amdgcn_s_setprio(0);

        __syncthreads();
        if (jt < 15) stage_k((jt + 1) * 64);

        float mt = sacc[0][0];
        #pragma unroll
        for (int n = 0; n < 4; ++n)
            #pragma unroll
            for (int r = 0; r < 4; ++r) mt = fmaxf(mt, sacc[n][r]);
        mt = fmaxf(mt, __shfl_xor(mt, 16));
        mt = fmaxf(mt, __shfl_xor(mt, 32));
        if (!__all(mt * 0.125f - mrow <= 8.f)) {
            float mnew = fmaxf(mrow, mt * 0.125f);
            float alpha = __expf(mrow - mnew);
            mrow = mnew;
            lrow *= alpha;
            #pragma unroll
            for (int r = 0; r < 4; ++r) {
                float a_r = __shfl(alpha, 4 * g + r);
                #pragma unroll
                for (int n2 = 0; n2 < 4; ++n2) xacc[n2][r] *= a_r;
            }
        }
        float rsum = 0.f;
        u16 pb[16];
        #pragma unroll
        for (int n = 0; n < 4; ++n)
            #pragma unroll
            for (int r = 0; r < 4; ++r) {
                float p = __expf(sacc[n][r] * 0.125f - mrow);
                rsum += p;
                pb[n * 4 + r] = f2bf(p);
            }
        rsum += __shfl_xor(rsum, 16);
        rsum += __shfl_xor(rsum, 32);
        lrow += rsum;

        {
            const int q = w * 16 + ql;
            #pragma unroll
            for (int n = 0; n < 4; ++n) {
                int c = 16 * n + 4 * g;
                *(u16x4*)(&ps[q * 64 + (c ^ ((q & 7) << 3))]) = *(const u16x4*)(&pb[n * 4]);
            }
        }
        asm volatile("s_waitcnt lgkmcnt(0)" ::: "memory");
        __builtin_amdgcn_sched_barrier(0);

        bf16x8 pa[2];
        {
            const int q = w * 16 + ql;
            #pragma unroll
            for (int ks = 0; ks < 2; ++ks) {
                int c = 32 * ks + 8 * g;
                pa[ks] = *(const bf16x8*)(&ps[q * 64 + (c ^ ((q & 7) << 3))]);
            }
        }

        __builtin_amdgcn_s_setprio(1);
        #pragma unroll
        for (int ks = 0; ks < 2; ++ks)
            #pragma unroll
            for (int n2 = 0; n2 < 4; ++n2) {
                int vrow = n2 * 16 + ql;
                int c2 = 32 * ks + 8 * g;
                bf16x8 bv = *(const bf16x8*)(&vsT[vrow * 64 + (c2 ^ ((vrow & 7) << 3))]);
                xacc[n2] = __builtin_amdgcn_mfma_f32_16x16x32_bf16(pa[ks], bv, xacc[n2], 0, 0, 0);
            }
        __builtin_amdgcn_s_setprio(0);

        __syncthreads();
        if (jt < 15) stage_v((jt + 1) * 64);
    }

    float linv[4];
    #pragma unroll
    for (int r = 0; r < 4; ++r) linv[r] = 1.f / __shfl(lrow, 4 * g + r);
    #pragma unroll
    for (int n2 = 0; n2 < 4; ++n2)
        #pragma unroll
        for (int r = 0; r < 4; ++r) {
            int qrow = q0 + w * 16 + 4 * g + r;
            int col = cb0 + n2 * 16 + ql;
            Og[(rbase + qrow) * D_ + col] = f2bf(xacc[n2][r] * linv[r]);
        }
}

// ---------------------------------------------------------------------------
// Flash attention (R2-verified version) for the fallback path.
// ---------------------------------------------------------------------------
__global__ __launch_bounds__(256) void attn_fwd(
    const u16* __restrict__ Qg, const u16* __restrict__ Kg,
    const u16* __restrict__ Vg, u16* __restrict__ Og)
{
    __shared__ u16 qs[64 * 64], ks2[64 * 64], vt[64 * 64], ps[64 * 64];
    const int tid = threadIdx.x, lane = tid & 63, w = tid >> 6;
    const int b = blockIdx.z, h = blockIdx.y, q0 = blockIdx.x * 64;
    const size_t rbase = (size_t)b * S_;
    const int cb0 = h * DK_;

    #pragma unroll
    for (int j = 0; j < 4; ++j) {
        int idx4 = tid + 256 * j;
        int r = idx4 >> 4, c = (idx4 & 15) * 4;
        u16x4 t = *(const u16x4*)(Qg + (rbase + q0 + r) * D_ + cb0 + c);
        *(u16x4*)(&qs[r * 64 + (c ^ ((r & 7) << 3))]) = t;
    }

    float mrow[4], lrow[4];
    f32x4 xacc[4] = {};
    #pragma unroll
    for (int r = 0; r < 4; ++r) { mrow[r] = -1e30f; lrow[r] = 0.f; }

    for (int jt = 0; jt < 16; ++jt) {
        const int kv0 = jt * 64;
        __syncthreads();
        #pragma unroll
        for (int j = 0; j < 4; ++j) {
            int idx4 = tid + 256 * j;
            int r = idx4 >> 4, c = (idx4 & 15) * 4;
            u16x4 t = *(const u16x4*)(Kg + (rbase + kv0 + r) * D_ + cb0 + c);
            *(u16x4*)(&ks2[r * 64 + (c ^ ((r & 7) << 3))]) = t;
            u16x4 tv = *(const u16x4*)(Vg + (rbase + kv0 + r) * D_ + cb0 + c);
            #pragma unroll
            for (int jj = 0; jj < 4; ++jj) {
                int d = c + jj;
                vt[d * 64 + (r ^ ((d & 7) << 3))] = tv[jj];
            }
        }
        __syncthreads();

        f32x4 sacc[4] = {};
        #pragma unroll
        for (int ks = 0; ks < 2; ++ks) {
            const int cb = ks * 32 + (lane >> 4) * 8;
            int qrow = w * 16 + (lane & 15);
            bf16x8 aq = *(const bf16x8*)(&qs[qrow * 64 + (cb ^ ((qrow & 7) << 3))]);
            #pragma unroll
            for (int n = 0; n < 4; ++n) {
                int krow = n * 16 + (lane & 15);
                bf16x8 bk = *(const bf16x8*)(&ks2[krow * 64 + (cb ^ ((krow & 7) << 3))]);
                sacc[n] = __builtin_amdgcn_mfma_f32_16x16x32_bf16(aq, bk, sacc[n], 0, 0, 0);
            }
        }

        #pragma unroll
        for (int r = 0; r < 4; ++r) {
            float mx = fmaxf(fmaxf(sacc[0][r], sacc[1][r]),
                             fmaxf(sacc[2][r], sacc[3][r]));
            mx = fmaxf(mx, __shfl_xor(mx, 1));
            mx = fmaxf(mx, __shfl_xor(mx, 2));
            mx = fmaxf(mx, __shfl_xor(mx, 4));
            mx = fmaxf(mx, __shfl_xor(mx, 8));
            float mnew = fmaxf(mrow[r], mx * 0.125f);
            float alpha = __expf(mrow[r] - mnew);
            float p[4], rsum = 0.f;
            #pragma unroll
            for (int n = 0; n < 4; ++n) { p[n] = __expf(sacc[n][r] * 0.125f - mnew); rsum += p[n]; }
            rsum += __shfl_xor(rsum, 1);
            rsum += __shfl_xor(rsum, 2);
            rsum += __shfl_xor(rsum, 4);
            rsum += __shfl_xor(rsum, 8);
            lrow[r] = lrow[r] * alpha + rsum;
            mrow[r] = mnew;
            int qrow = w * 16 + (lane >> 4) * 4 + r;
            #pragma unroll
            for (int n = 0; n < 4; ++n) {
                xacc[n][r] *= alpha;
                int col = n * 16 + (lane & 15);
                ps[qrow * 64 + (col ^ ((qrow & 7) << 3))] = f2bf(p[n]);
            }
        }
        __syncthreads();

        #pragma unroll
        for (int ks = 0; ks < 2; ++ks) {
            const int cb = ks * 32 + (lane >> 4) * 8;
            int prow = w * 16 + (lane & 15);
            bf16x8 ap = *(const bf16x8*)(&ps[prow * 64 + (cb ^ ((prow & 7) << 3))]);
            #pragma unroll
            for (int n = 0; n < 4; ++n) {
                int vrow = n * 16 + (lane & 15);
                bf16x8 bv = *(const bf16x8*)(&vt[vrow * 64 + (cb ^ ((vrow & 7) << 3))]);
                xacc[n] = __builtin_amdgcn_mfma_f32_16x16x32_bf16(ap, bv, xacc[n], 0, 0, 0);
            }
        }
    }

    #pragma unroll
    for (int n = 0; n < 4; ++n)
        #pragma unroll
        for (int r = 0; r < 4; ++r) {
            int qrow = q0 + w * 16 + (lane >> 4) * 4 + r;
            int col = cb0 + n * 16 + (lane & 15);
            Og[(rbase + qrow) * D_ + col] = f2bf(xacc[n][r] / lrow[r]);
        }
}

// ---------------------------------------------------------------------------
// LN fused v2: y = LN(bf16(Y) + bf16(resid)) * gamma + beta, fp32 out.
// Residual comes from the PACKED q (bf16, 8MB) instead of fp32 query (16MB).
// ---------------------------------------------------------------------------
__global__ __launch_bounds__(256) void ln_fused(
    const u16* __restrict__ Yb, const u16* __restrict__ residb,
    const float* __restrict__ g, const float* __restrict__ bt,
    float* __restrict__ out)
{
    __shared__ float red[2][4];
    const int row = blockIdx.x, tid = threadIdx.x;
    u16x4 yv = *(const u16x4*)(Yb + (size_t)row * D_ + tid * 4);
    u16x4 rv = *(const u16x4*)(residb + (size_t)row * D_ + tid * 4);
    float x0 = bf2f(yv[0]) + bf2f(rv[0]);
    float x1 = bf2f(yv[1]) + bf2f(rv[1]);
    float x2 = bf2f(yv[2]) + bf2f(rv[2]);
    float x3 = bf2f(yv[3]) + bf2f(rv[3]);
    float s = x0 + x1 + x2 + x3;
    float q = x0 * x0 + x1 * x1 + x2 * x2 + x3 * x3;
    #pragma unroll
    for (int m = 1; m < 64; m <<= 1) { s += __shfl_xor(s, m); q += __shfl_xor(q, m); }
    const int w = tid >> 6, lane = tid & 63;
    if (lane == 0) { red[0][w] = s; red[1][w] = q; }
    __syncthreads();
    s = red[0][0] + red[0][1] + red[0][2] + red[0][3];
    q = red[1][0] + red[1][1] + red[1][2] + red[1][3];
    float mu = s * (1.f / 1024.f);
    float var = q * (1.f / 1024.f) - mu * mu;
    float rstd = rsqrtf(var + 1e-6f);
    float4 gv = *(const float4*)(g + tid * 4);
    float4 bv = *(const float4*)(bt + tid * 4);
    float4 o;
    o.x = (x0 - mu) * rstd * gv.x + bv.x;
    o.y = (x1 - mu) * rstd * gv.y + bv.y;
    o.z = (x2 - mu) * rstd * gv.z + bv.z;
    o.w = (x3 - mu) * rstd * gv.w + bv.w;
    *(float4*)(out + (size_t)row * D_ + tid * 4) = o;
}

// ---------------------------------------------------------------------------
// LayerNorm in-place on fp32 [4096][1024] (fallback path).
// ---------------------------------------------------------------------------
__global__ __launch_bounds__(256) void ln_inplace(
    float* __restrict__ Y, const float* __restrict__ g, const float* __restrict__ bt)
{
    __shared__ float red[2][4];
    const int row = blockIdx.x, tid = threadIdx.x;
    float4 v = *(const float4*)(Y + (size_t)row * D_ + tid * 4);
    float s = v.x + v.y + v.z + v.w;
    float q = v.x * v.x + v.y * v.y + v.z * v.z + v.w * v.w;
    #pragma unroll
    for (int m = 1; m < 64; m <<= 1) { s += __shfl_xor(s, m); q += __shfl_xor(q, m); }
    const int w = tid >> 6, lane = tid & 63;
    if (lane == 0) { red[0][w] = s; red[1][w] = q; }
    __syncthreads();
    s = red[0][0] + red[0][1] + red[0][2] + red[0][3];
    q = red[1][0] + red[1][1] + red[1][2] + red[1][3];
    float mu = s * (1.f / 1024.f);
    float var = q * (1.f / 1024.f) - mu * mu;
    float rstd = rsqrtf(var + 1e-6f);
    float4 gv = *(const float4*)(g + tid * 4);
    float4 bv = *(const float4*)(bt + tid * 4);
    v.x = (v.x - mu) * rstd * gv.x + bv.x;
    v.y = (v.y - mu) * rstd * gv.y + bv.y;
    v.z = (v.z - mu) * rstd * gv.z + bv.z;
    v.w = (v.w - mu) * rstd * gv.w + bv.w;
    *(float4*)(Y + (size_t)row * D_ + tid * 4) = v;
}

extern "C" void kernel_launch(void* const* d_in, const int* in_sizes, int n_in,
                              void* d_out, int out_size, void* d_ws, size_t ws_size,
                              hipStream_t stream)
{
    const float* query = (const float*)d_in[0];
    const float* key   = (const float*)d_in[1];
    const float* value = (const float*)d_in[2];
    const float* Wq    = (const float*)d_in[3];
    const float* Wk    = (const float*)d_in[4];
    const float* Wv    = (const float*)d_in[5];
    const float* Wo    = (const float*)d_in[6];
    const float* gamma = (const float*)d_in[7];
    const float* beta  = (const float*)d_in[8];
    float* out = (float*)d_out;

    const size_t ACT = (size_t)MROWS * D_;
    const size_t WSZ = (size_t)D_ * D_;
    const size_t NEED = (3 * ACT + 4 * WSZ + 3 * ACT) * 2;   // 58,720,256 B

    if (ws_size >= NEED) {
        // layout (bf16): actb = [q-packed | k-packed | v-packed] | wb | pb
        // After QKV gemm: k,v-packed are dead. q-packed KEPT as bf16 residual.
        //   Ap (attn out)  -> v region (actb + 2*ACT)
        //   Yb (Wo out)    -> k region (actb + ACT)
        u16* actb = (u16*)d_ws;
        u16* wb   = actb + 3 * ACT;
        u16* pb   = wb + 4 * WSZ;      // Qp | Kp | Vt (transposed)
        u16* Ap   = actb + 2 * ACT;
        u16* Yb   = actb + ACT;

        pack_bf16<<<2048, 256, 0, stream>>>(query, key, value, Wq, Wk, Wv, Wo, actb, wb);
        gemm_fast<128, false, true><<<dim3(8, 32, 3), 256, 0, stream>>>(actb, wb, pb, nullptr, nullptr);
        attn_fwd6<<<512, 512, 0, stream>>>(pb, pb + ACT, pb + 2 * ACT, Ap);
        gemm_fast<64, false, false><<<dim3(8, 64, 1), 256, 0, stream>>>(Ap, wb + 3 * WSZ, Yb, nullptr, nullptr);
        ln_fused<<<MROWS, 256, 0, stream>>>(Yb, actb, gamma, beta, out);
    } else {
        u16* Qp = (u16*)d_ws;
        u16* Kp = Qp + ACT;
        u16* Vp = Kp + ACT;
        u16* Ap = Vp + ACT;
        dim3 gg(D_ / 128, MROWS / 128);
        gemm_bt<false, false><<<gg, 256, 0, stream>>>(query, Wq, Qp, nullptr, nullptr, MROWS, D_, D_);
        gemm_bt<false, false><<<gg, 256, 0, stream>>>(key,   Wk, Kp, nullptr, nullptr, MROWS, D_, D_);
        gemm_bt<false, false><<<gg, 256, 0, stream>>>(value, Wv, Vp, nullptr, nullptr, MROWS, D_, D_);
        attn_fwd<<<dim3(S_ / 64, H_, B_), 256, 0, stream>>>(Qp, Kp, Vp, Ap);
        gemm_bt<true, true><<<gg, 256, 0, stream>>>(Ap, Wo, nullptr, out, query, MROWS, D_, D_);
        ln_inplace<<<MROWS, 256, 0, stream>>>(out, gamma, beta);
    }
}

// Round 15
// 105.970 us; speedup vs baseline: 1.6344x; 1.0562x over previous
//
#include <hip/hip_runtime.h>
#include <hip/hip_bf16.h>

// Fused MHA block: y = LN(x @ attn + residual)
// B=4 S=1024 D=1024 H=16 DK=64. fp32 I/O, bf16 MFMA internally.
#define B_ 4
#define S_ 1024
#define D_ 1024
#define H_ 16
#define DK_ 64
#define MROWS (B_*S_)   // 4096

typedef short bf16x8 __attribute__((ext_vector_type(8)));
typedef float f32x4 __attribute__((ext_vector_type(4)));
typedef unsigned short u16;
typedef unsigned u32;
typedef u16 u16x4 __attribute__((ext_vector_type(4)));

__device__ __forceinline__ u16 f2bf(float f) {
    union { float f; unsigned u; } v; v.f = f;
    unsigned u = v.u;
    u += 0x7fff + ((u >> 16) & 1);   // RNE
    return (u16)(u >> 16);
}
__device__ __forceinline__ float bf2f(u16 h) {
    union { unsigned u; float f; } v; v.u = ((unsigned)h) << 16;
    return v.f;
}

__device__ __forceinline__ void gld_lds16(const u16* gp, u16* lp) {
    __builtin_amdgcn_global_load_lds(
        (const __attribute__((address_space(1))) void*)gp,
        (__attribute__((address_space(3))) void*)lp,
        16, 0, 0);
}

// ---------------------------------------------------------------------------
// Pack: fp32 -> bf16 for activations and weights (R6-verified).
// ---------------------------------------------------------------------------
__global__ __launch_bounds__(256) void pack_bf16(
    const float* __restrict__ q, const float* __restrict__ k, const float* __restrict__ v,
    const float* __restrict__ wq, const float* __restrict__ wk,
    const float* __restrict__ wv, const float* __restrict__ wo,
    u16* __restrict__ act_dst, u16* __restrict__ w_dst)
{
    const int NACT = 3 * MROWS * D_;
    const int NW   = 4 * D_ * D_;
    for (int c = blockIdx.x * blockDim.x + threadIdx.x;
         c < (NACT + NW) / 4; c += gridDim.x * blockDim.x) {
        int e = c * 4;
        const float* s; u16* d;
        if (e < NACT) {
            int t = e >> 22;
            int off = e & (4194304 - 1);
            s = (t == 0 ? q : t == 1 ? k : v) + off;
            d = act_dst + e;
        } else {
            int e2 = e - NACT;
            int t = e2 >> 20;
            int off = e2 & (1048576 - 1);
            s = (t == 0 ? wq : t == 1 ? wk : t == 2 ? wv : wo) + off;
            d = w_dst + e2;
        }
        float4 tv = *(const float4*)s;
        u16x4 o; o[0]=f2bf(tv.x); o[1]=f2bf(tv.y); o[2]=f2bf(tv.z); o[3]=f2bf(tv.w);
        *(u16x4*)d = o;
    }
}

// ---------------------------------------------------------------------------
// QKV GEMM v6: 8 waves (512 thr), 128x128 tile, wave grid 4m x 2n (each wave
// 32x64, acc 2x4). Same R10-verified skeleton: A-reg-preload + B-dbuf,
// 2 barriers/K-step, 48KB LDS -> 3 blocks/CU = 24 waves/CU.
// z==2 (V projection) stores C transposed (Vt[d][token]).
// ---------------------------------------------------------------------------
__global__ __launch_bounds__(512) void gemm_qkv8(
    const u16* __restrict__ Ab, const u16* __restrict__ Wb,
    u16* __restrict__ Cb)
{
    __shared__ u16 ldsA[128 * 64];        // 16KB
    __shared__ u16 ldsB[2][128 * 64];     // 32KB

    // XCD-chunked remap (nwg = 768, %8==0 -> bijective)
    const int gx = gridDim.x, gy = gridDim.y;
    const int nwg = gx * gy * gridDim.z;
    const int flat = blockIdx.x + gx * (blockIdx.y + gy * blockIdx.z);
    const int f = (flat & 7) * (nwg >> 3) + (flat >> 3);
    const int bx = f % gx;
    const int rem = f / gx;
    const int by = rem % gy;
    const int z = rem / gy;

    Ab += (size_t)z * MROWS * D_;
    Wb += (size_t)z * D_ * D_;

    const int tid = threadIdx.x, lane = tid & 63, wid = tid >> 6;  // wid 0..7
    const int wr = wid >> 1, wc = wid & 1;                          // 4m x 2n
    const int g = lane >> 4, ql = lane & 15;
    const int m0 = by * 128, n0 = bx * 128;

    auto stageA = [&](int it) {
        const int kt = it * 64;
        #pragma unroll
        for (int j = 0; j < 2; ++j) {
            int ch = j * 512 + tid;
            int row = ch >> 3, c8 = (ch & 7) ^ (row & 7);
            gld_lds16(Ab + (size_t)(m0 + row) * 1024 + kt + c8 * 8,
                      &ldsA[(j * 512 + wid * 64) * 8]);
        }
    };
    auto stageB = [&](int p, int it) {
        const int kt = it * 64;
        #pragma unroll
        for (int j = 0; j < 2; ++j) {
            int ch = j * 512 + tid;
            int row = ch >> 3, c8 = (ch & 7) ^ (row & 7);
            gld_lds16(Wb + (size_t)(n0 + row) * 1024 + kt + c8 * 8,
                      &ldsB[p][(j * 512 + wid * 64) * 8]);
        }
    };

    f32x4 acc[2][4] = {};

    stageA(0);
    stageB(0, 0);
    __syncthreads();

    for (int it = 0; it < 16; ++it) {
        const int bcur = it & 1;

        // preload this tile's A fragments (rows wr*32 + m*16 + ql)
        bf16x8 af[2][2];
        #pragma unroll
        for (int ks = 0; ks < 2; ++ks) {
            const int cb = ks * 32 + g * 8;
            #pragma unroll
            for (int m = 0; m < 2; ++m) {
                int row = wr * 32 + m * 16 + ql;
                af[ks][m] = *(const bf16x8*)(&ldsA[row * 64 + (cb ^ ((row & 7) << 3))]);
            }
        }
        __syncthreads();                 // all waves' A reads retired

        if (it < 15) {
            stageA(it + 1);              // overwrite ldsA (frags in regs)
            stageB(bcur ^ 1, it + 1);    // fill other B buffer
        }
        __builtin_amdgcn_sched_barrier(0);

        #pragma unroll
        for (int ks = 0; ks < 2; ++ks) {
            const int cb = ks * 32 + g * 8;
            bf16x8 bfr[4];
            #pragma unroll
            for (int n = 0; n < 4; ++n) {
                int row = wc * 64 + n * 16 + ql;
                bfr[n] = *(const bf16x8*)(&ldsB[bcur][row * 64 + (cb ^ ((row & 7) << 3))]);
            }
            #pragma unroll
            for (int m = 0; m < 2; ++m)
                #pragma unroll
                for (int n = 0; n < 4; ++n)
                    acc[m][n] = __builtin_amdgcn_mfma_f32_16x16x32_bf16(
                        af[ks][m], bfr[n], acc[m][n], 0, 0, 0);
        }

        __syncthreads();                 // next tile's A/B landed
    }

    // C/D map: col = lane&15, row = (lane>>4)*4 + reg
    if (z == 2) {
        u16* Cz = Cb + 2 * (size_t)MROWS * D_;
        #pragma unroll
        for (int m = 0; m < 2; ++m)
            #pragma unroll
            for (int n = 0; n < 4; ++n) {
                u16x4 o;
                #pragma unroll
                for (int r = 0; r < 4; ++r) o[r] = f2bf(acc[m][n][r]);
                int grow = m0 + wr * 32 + m * 16 + g * 4;   // token
                int gcol = n0 + wc * 64 + n * 16 + ql;      // d
                *(u16x4*)(&Cz[(size_t)gcol * MROWS + grow]) = o;
            }
    } else {
        u16* Cz = Cb + (size_t)z * MROWS * D_;
        #pragma unroll
        for (int m = 0; m < 2; ++m)
            #pragma unroll
            for (int n = 0; n < 4; ++n)
                #pragma unroll
                for (int r = 0; r < 4; ++r) {
                    int grow = m0 + wr * 32 + m * 16 + g * 4 + r;
                    int gcol = n0 + wc * 64 + n * 16 + ql;
                    Cz[(size_t)grow * 1024 + gcol] = f2bf(acc[m][n][r]);
                }
    }
}

// ---------------------------------------------------------------------------
// GEMM v3 (R10-verified): A-reg-preload + B-double-buffer, 256 threads.
// Used for the Wo projection (BM=64, bf16 C out).
// ---------------------------------------------------------------------------
template<int BM, bool EPI_RESID, bool VT>
__global__ __launch_bounds__(256) void gemm_fast(
    const u16* __restrict__ Ab, const u16* __restrict__ Wb,
    u16* __restrict__ Cb, float* __restrict__ Cf, const float* __restrict__ resid)
{
    constexpr int WN = (BM == 128) ? 2 : 4;
    constexpr int WCOLS = 128 / WN;
    constexpr int NR = WCOLS / 16;
    __shared__ u16 ldsA[BM * 64];
    __shared__ u16 ldsB[2][128 * 64];

    const int gx = gridDim.x, gy = gridDim.y, gz = gridDim.z;
    const int nwg = gx * gy * gz;
    const int flat = blockIdx.x + gx * (blockIdx.y + gy * blockIdx.z);
    const int f = (flat & 7) * (nwg >> 3) + (flat >> 3);
    const int bx = f % gx;
    const int rem = f / gx;
    const int by = rem % gy;
    const int z = rem / gy;

    Ab += (size_t)z * MROWS * D_;
    Wb += (size_t)z * D_ * D_;
    const u16* CbT = Cb + (EPI_RESID ? 0 : (size_t)z * MROWS * D_);
    u16* Cbz = (u16*)CbT;

    const int tid = threadIdx.x, lane = tid & 63, wid = tid >> 6;
    const int wr = (BM == 128) ? (wid >> 1) : 0;
    const int wc = (BM == 128) ? (wid & 1) : wid;
    const int m0 = by * BM, n0 = bx * 128;
    const int wbase = wid * 64;

    auto stageA = [&](int it) {
        const int kt = it * 64;
        #pragma unroll
        for (int j = 0; j < BM / 32; ++j) {
            int ch = j * 256 + tid;
            int row = ch >> 3, c8 = (ch & 7) ^ (row & 7);
            gld_lds16(Ab + (size_t)(m0 + row) * 1024 + kt + c8 * 8,
                      &ldsA[(j * 256 + wbase) * 8]);
        }
    };
    auto stageB = [&](int p, int it) {
        const int kt = it * 64;
        #pragma unroll
        for (int j = 0; j < 4; ++j) {
            int ch = j * 256 + tid;
            int row = ch >> 3, c8 = (ch & 7) ^ (row & 7);
            gld_lds16(Wb + (size_t)(n0 + row) * 1024 + kt + c8 * 8,
                      &ldsB[p][(j * 256 + wbase) * 8]);
        }
    };

    f32x4 acc[4][NR] = {};

    stageA(0);
    stageB(0, 0);
    __syncthreads();

    for (int it = 0; it < 16; ++it) {
        const int bcur = it & 1;

        bf16x8 af[2][4];
        #pragma unroll
        for (int ks = 0; ks < 2; ++ks) {
            const int cb = ks * 32 + (lane >> 4) * 8;
            #pragma unroll
            for (int m = 0; m < 4; ++m) {
                int row = wr * 64 + m * 16 + (lane & 15);
                af[ks][m] = *(const bf16x8*)(&ldsA[row * 64 + (cb ^ ((row & 7) << 3))]);
            }
        }
        __syncthreads();

        if (it < 15) {
            stageA(it + 1);
            stageB(bcur ^ 1, it + 1);
        }
        __builtin_amdgcn_sched_barrier(0);

        #pragma unroll
        for (int ks = 0; ks < 2; ++ks) {
            const int cb = ks * 32 + (lane >> 4) * 8;
            bf16x8 bfr[NR];
            #pragma unroll
            for (int n = 0; n < NR; ++n) {
                int row = wc * WCOLS + n * 16 + (lane & 15);
                bfr[n] = *(const bf16x8*)(&ldsB[bcur][row * 64 + (cb ^ ((row & 7) << 3))]);
            }
            #pragma unroll
            for (int m = 0; m < 4; ++m)
                #pragma unroll
                for (int n = 0; n < NR; ++n)
                    acc[m][n] = __builtin_amdgcn_mfma_f32_16x16x32_bf16(
                        af[ks][m], bfr[n], acc[m][n], 0, 0, 0);
        }

        __syncthreads();
    }

    if (VT && z == 2) {
        #pragma unroll
        for (int m = 0; m < 4; ++m)
            #pragma unroll
            for (int n = 0; n < NR; ++n) {
                u16x4 o;
                #pragma unroll
                for (int r = 0; r < 4; ++r) o[r] = f2bf(acc[m][n][r]);
                int grow = m0 + wr * 64 + m * 16 + (lane >> 4) * 4;
                int gcol = n0 + wc * WCOLS + n * 16 + (lane & 15);
                *(u16x4*)(&Cbz[(size_t)gcol * MROWS + grow]) = o;
            }
    } else {
        #pragma unroll
        for (int m = 0; m < 4; ++m)
            #pragma unroll
            for (int n = 0; n < NR; ++n)
                #pragma unroll
                for (int r = 0; r < 4; ++r) {
                    int grow = m0 + wr * 64 + m * 16 + (lane >> 4) * 4 + r;
                    int gcol = n0 + wc * WCOLS + n * 16 + (lane & 15);
                    if (EPI_RESID)
                        Cf[(size_t)grow * 1024 + gcol] = acc[m][n][r] + resid[(size_t)grow * 1024 + gcol];
                    else
                        Cbz[(size_t)grow * 1024 + gcol] = f2bf(acc[m][n][r]);
                }
    }
}

// ---------------------------------------------------------------------------
// Fallback GEMM (round-1 path), unchanged.
// ---------------------------------------------------------------------------
template<bool A_BF16, bool EPI_RESID>
__global__ __launch_bounds__(256) void gemm_bt(
    const void* __restrict__ Av, const float* __restrict__ Bw,
    u16* __restrict__ Cb, float* __restrict__ Cf,
    const float* __restrict__ resid, int M, int N, int K)
{
    __shared__ u16 lds[2][128 * 64];
    const int tid  = threadIdx.x;
    const int lane = tid & 63;
    const int wid  = tid >> 6;
    const int wr = wid >> 1, wc = wid & 1;
    const int m0 = blockIdx.y * 128, n0 = blockIdx.x * 128;

    f32x4 acc[4][4] = {};

    for (int kt = 0; kt < K; kt += 64) {
        #pragma unroll
        for (int j = 0; j < 8; ++j) {
            int idx4 = tid + 256 * j;
            int r = idx4 >> 4;
            int c = (idx4 & 15) * 4;
            u16x4 aw, bw;
            if (A_BF16) {
                const u16* Ab2 = (const u16*)Av;
                aw = *(const u16x4*)(Ab2 + (size_t)(m0 + r) * K + kt + c);
            } else {
                const float* Af = (const float*)Av;
                float4 t = *(const float4*)(Af + (size_t)(m0 + r) * K + kt + c);
                aw[0] = f2bf(t.x); aw[1] = f2bf(t.y); aw[2] = f2bf(t.z); aw[3] = f2bf(t.w);
            }
            {
                float4 t = *(const float4*)(Bw + (size_t)(n0 + r) * K + kt + c);
                bw[0] = f2bf(t.x); bw[1] = f2bf(t.y); bw[2] = f2bf(t.z); bw[3] = f2bf(t.w);
            }
            int sa = r * 64 + (c ^ ((r & 7) << 3));
            *(u16x4*)(&lds[0][sa]) = aw;
            *(u16x4*)(&lds[1][sa]) = bw;
        }
        __syncthreads();
        #pragma unroll
        for (int ks = 0; ks < 2; ++ks) {
            const int cb = ks * 32 + (lane >> 4) * 8;
            bf16x8 af[4], bfr[4];
            #pragma unroll
            for (int m = 0; m < 4; ++m) {
                int row = wr * 64 + m * 16 + (lane & 15);
                af[m] = *(const bf16x8*)(&lds[0][row * 64 + (cb ^ ((row & 7) << 3))]);
            }
            #pragma unroll
            for (int n = 0; n < 4; ++n) {
                int row = wc * 64 + n * 16 + (lane & 15);
                bfr[n] = *(const bf16x8*)(&lds[1][row * 64 + (cb ^ ((row & 7) << 3))]);
            }
            #pragma unroll
            for (int m = 0; m < 4; ++m)
                #pragma unroll
                for (int n = 0; n < 4; ++n)
                    acc[m][n] = __builtin_amdgcn_mfma_f32_16x16x32_bf16(
                        af[m], bfr[n], acc[m][n], 0, 0, 0);
        }
        __syncthreads();
    }

    #pragma unroll
    for (int m = 0; m < 4; ++m)
        #pragma unroll
        for (int n = 0; n < 4; ++n)
            #pragma unroll
            for (int r = 0; r < 4; ++r) {
                int grow = m0 + wr * 64 + m * 16 + (lane >> 4) * 4 + r;
                int gcol = n0 + wc * 64 + n * 16 + (lane & 15);
                float v = acc[m][n][r];
                if (EPI_RESID)
                    Cf[(size_t)grow * N + gcol] = v + resid[(size_t)grow * N + gcol];
                else
                    Cb[(size_t)grow * N + gcol] = f2bf(v);
            }
}

// ---------------------------------------------------------------------------
// Flash attention v6 (R9-verified): swapped QK^T, in-lane softmax,
// wave-private P, Vt-from-global, split-stage pipeline, Q-in-reg, defer-max.
// ---------------------------------------------------------------------------
__global__ __launch_bounds__(512, 4) void attn_fwd6(
    const u16* __restrict__ Qg, const u16* __restrict__ Kg,
    const u16* __restrict__ Vt, u16* __restrict__ Og)
{
    __shared__ u16 ks2[64 * 64];
    __shared__ u16 vsT[64 * 64];
    __shared__ u16 ps[128 * 64];

    const int tid = threadIdx.x, lane = tid & 63, w = tid >> 6;
    const int g = lane >> 4, ql = lane & 15;

    const int bid = blockIdx.x;
    const int f = (bid & 7) * 64 + (bid >> 3);
    const int qt = f & 7, h = (f >> 3) & 15, b = f >> 7;
    const int q0 = qt * 128;
    const size_t rbase = (size_t)b * S_;
    const int cb0 = h * DK_;

    bf16x8 qb[2];
    {
        const u16* qp = Qg + (rbase + q0 + w * 16 + ql) * D_ + cb0 + 8 * g;
        qb[0] = *(const bf16x8*)(qp);
        qb[1] = *(const bf16x8*)(qp + 32);
    }

    auto stage_k = [&](int kv0) {
        int row = tid >> 3, c8 = (tid & 7) ^ (row & 7);
        gld_lds16(Kg + (rbase + kv0 + row) * D_ + cb0 + c8 * 8, &ks2[w * 512]);
    };
    auto stage_v = [&](int kv0) {
        int row = tid >> 3, c8 = (tid & 7) ^ (row & 7);
        gld_lds16(Vt + (size_t)(cb0 + row) * MROWS + rbase + kv0 + c8 * 8, &vsT[w * 512]);
    };

    stage_k(0);
    stage_v(0);
    __syncthreads();

    float mrow = -1e30f, lrow = 0.f;
    f32x4 xacc[4] = {};

    for (int jt = 0; jt < 16; ++jt) {
        f32x4 sacc[4] = {};
        __builtin_amdgcn_s_setprio(1);
        #pragma unroll
        for (int ks = 0; ks < 2; ++ks) {
            #pragma unroll
            for (int n = 0; n < 4; ++n) {
                int krow = n * 16 + ql;
                int c = 32 * ks + 8 * g;
                bf16x8 kf = *(const bf16x8*)(&ks2[krow * 64 + (c ^ ((krow & 7) << 3))]);
                sacc[n] = __builtin_amdgcn_mfma_f32_16x16x32_bf16(kf, qb[ks], sacc[n], 0, 0, 0);
            }
        }
        __builtin_amdgcn_s_setprio(0);

        __syncthreads();
        if (jt < 15) stage_k((jt + 1) * 64);

        float mt = sacc[0][0];
        #pragma unroll
        for (int n = 0; n < 4; ++n)
            #pragma unroll
            for (int r = 0; r < 4; ++r) mt = fmaxf(mt, sacc[n][r]);
        mt = fmaxf(mt, __shfl_xor(mt, 16));
        mt = fmaxf(mt, __shfl_xor(mt, 32));
        if (!__all(mt * 0.125f - mrow <= 8.f)) {
            float mnew = fmaxf(mrow, mt * 0.125f);
            float alpha = __expf(mrow - mnew);
            mrow = mnew;
            lrow *= alpha;
            #pragma unroll
            for (int r = 0; r < 4; ++r) {
                float a_r = __shfl(alpha, 4 * g + r);
                #pragma unroll
                for (int n2 = 0; n2 < 4; ++n2) xacc[n2][r] *= a_r;
            }
        }
        float rsum = 0.f;
        u16 pb[16];
        #pragma unroll
        for (int n = 0; n < 4; ++n)
            #pragma unroll
            for (int r = 0; r < 4; ++r) {
                float p = __expf(sacc[n][r] * 0.125f - mrow);
                rsum += p;
                pb[n * 4 + r] = f2bf(p);
            }
        rsum += __shfl_xor(rsum, 16);
        rsum += __shfl_xor(rsum, 32);
        lrow += rsum;

        {
            const int q = w * 16 + ql;
            #pragma unroll
            for (int n = 0; n < 4; ++n) {
                int c = 16 * n + 4 * g;
                *(u16x4*)(&ps[q * 64 + (c ^ ((q & 7) << 3))]) = *(const u16x4*)(&pb[n * 4]);
            }
        }
        asm volatile("s_waitcnt lgkmcnt(0)" ::: "memory");
        __builtin_amdgcn_sched_barrier(0);

        bf16x8 pa[2];
        {
            const int q = w * 16 + ql;
            #pragma unroll
            for (int ks = 0; ks < 2; ++ks) {
                int c = 32 * ks + 8 * g;
                pa[ks] = *(const bf16x8*)(&ps[q * 64 + (c ^ ((q & 7) << 3))]);
            }
        }

        __builtin_amdgcn_s_setprio(1);
        #pragma unroll
        for (int ks = 0; ks < 2; ++ks)
            #pragma unroll
            for (int n2 = 0; n2 < 4; ++n2) {
                int vrow = n2 * 16 + ql;
                int c2 = 32 * ks + 8 * g;
                bf16x8 bv = *(const bf16x8*)(&vsT[vrow * 64 + (c2 ^ ((vrow & 7) << 3))]);
                xacc[n2] = __builtin_amdgcn_mfma_f32_16x16x32_bf16(pa[ks], bv, xacc[n2], 0, 0, 0);
            }
        __builtin_amdgcn_s_setprio(0);

        __syncthreads();
        if (jt < 15) stage_v((jt + 1) * 64);
    }

    float linv[4];
    #pragma unroll
    for (int r = 0; r < 4; ++r) linv[r] = 1.f / __shfl(lrow, 4 * g + r);
    #pragma unroll
    for (int n2 = 0; n2 < 4; ++n2)
        #pragma unroll
        for (int r = 0; r < 4; ++r) {
            int qrow = q0 + w * 16 + 4 * g + r;
            int col = cb0 + n2 * 16 + ql;
            Og[(rbase + qrow) * D_ + col] = f2bf(xacc[n2][r] * linv[r]);
        }
}

// ---------------------------------------------------------------------------
// Flash attention (R2-verified version) for the fallback path.
// ---------------------------------------------------------------------------
__global__ __launch_bounds__(256) void attn_fwd(
    const u16* __restrict__ Qg, const u16* __restrict__ Kg,
    const u16* __restrict__ Vg, u16* __restrict__ Og)
{
    __shared__ u16 qs[64 * 64], ks2[64 * 64], vt[64 * 64], ps[64 * 64];
    const int tid = threadIdx.x, lane = tid & 63, w = tid >> 6;
    const int b = blockIdx.z, h = blockIdx.y, q0 = blockIdx.x * 64;
    const size_t rbase = (size_t)b * S_;
    const int cb0 = h * DK_;

    #pragma unroll
    for (int j = 0; j < 4; ++j) {
        int idx4 = tid + 256 * j;
        int r = idx4 >> 4, c = (idx4 & 15) * 4;
        u16x4 t = *(const u16x4*)(Qg + (rbase + q0 + r) * D_ + cb0 + c);
        *(u16x4*)(&qs[r * 64 + (c ^ ((r & 7) << 3))]) = t;
    }

    float mrow[4], lrow[4];
    f32x4 xacc[4] = {};
    #pragma unroll
    for (int r = 0; r < 4; ++r) { mrow[r] = -1e30f; lrow[r] = 0.f; }

    for (int jt = 0; jt < 16; ++jt) {
        const int kv0 = jt * 64;
        __syncthreads();
        #pragma unroll
        for (int j = 0; j < 4; ++j) {
            int idx4 = tid + 256 * j;
            int r = idx4 >> 4, c = (idx4 & 15) * 4;
            u16x4 t = *(const u16x4*)(Kg + (rbase + kv0 + r) * D_ + cb0 + c);
            *(u16x4*)(&ks2[r * 64 + (c ^ ((r & 7) << 3))]) = t;
            u16x4 tv = *(const u16x4*)(Vg + (rbase + kv0 + r) * D_ + cb0 + c);
            #pragma unroll
            for (int jj = 0; jj < 4; ++jj) {
                int d = c + jj;
                vt[d * 64 + (r ^ ((d & 7) << 3))] = tv[jj];
            }
        }
        __syncthreads();

        f32x4 sacc[4] = {};
        #pragma unroll
        for (int ks = 0; ks < 2; ++ks) {
            const int cb = ks * 32 + (lane >> 4) * 8;
            int qrow = w * 16 + (lane & 15);
            bf16x8 aq = *(const bf16x8*)(&qs[qrow * 64 + (cb ^ ((qrow & 7) << 3))]);
            #pragma unroll
            for (int n = 0; n < 4; ++n) {
                int krow = n * 16 + (lane & 15);
                bf16x8 bk = *(const bf16x8*)(&ks2[krow * 64 + (cb ^ ((krow & 7) << 3))]);
                sacc[n] = __builtin_amdgcn_mfma_f32_16x16x32_bf16(aq, bk, sacc[n], 0, 0, 0);
            }
        }

        #pragma unroll
        for (int r = 0; r < 4; ++r) {
            float mx = fmaxf(fmaxf(sacc[0][r], sacc[1][r]),
                             fmaxf(sacc[2][r], sacc[3][r]));
            mx = fmaxf(mx, __shfl_xor(mx, 1));
            mx = fmaxf(mx, __shfl_xor(mx, 2));
            mx = fmaxf(mx, __shfl_xor(mx, 4));
            mx = fmaxf(mx, __shfl_xor(mx, 8));
            float mnew = fmaxf(mrow[r], mx * 0.125f);
            float alpha = __expf(mrow[r] - mnew);
            float p[4], rsum = 0.f;
            #pragma unroll
            for (int n = 0; n < 4; ++n) { p[n] = __expf(sacc[n][r] * 0.125f - mnew); rsum += p[n]; }
            rsum += __shfl_xor(rsum, 1);
            rsum += __shfl_xor(rsum, 2);
            rsum += __shfl_xor(rsum, 4);
            rsum += __shfl_xor(rsum, 8);
            lrow[r] = lrow[r] * alpha + rsum;
            mrow[r] = mnew;
            int qrow = w * 16 + (lane >> 4) * 4 + r;
            #pragma unroll
            for (int n = 0; n < 4; ++n) {
                xacc[n][r] *= alpha;
                int col = n * 16 + (lane & 15);
                ps[qrow * 64 + (col ^ ((qrow & 7) << 3))] = f2bf(p[n]);
            }
        }
        __syncthreads();

        #pragma unroll
        for (int ks = 0; ks < 2; ++ks) {
            const int cb = ks * 32 + (lane >> 4) * 8;
            int prow = w * 16 + (lane & 15);
            bf16x8 ap = *(const bf16x8*)(&ps[prow * 64 + (cb ^ ((prow & 7) << 3))]);
            #pragma unroll
            for (int n = 0; n < 4; ++n) {
                int vrow = n * 16 + (lane & 15);
                bf16x8 bv = *(const bf16x8*)(&vt[vrow * 64 + (cb ^ ((vrow & 7) << 3))]);
                xacc[n] = __builtin_amdgcn_mfma_f32_16x16x32_bf16(ap, bv, xacc[n], 0, 0, 0);
            }
        }
    }

    #pragma unroll
    for (int n = 0; n < 4; ++n)
        #pragma unroll
        for (int r = 0; r < 4; ++r) {
            int qrow = q0 + w * 16 + (lane >> 4) * 4 + r;
            int col = cb0 + n * 16 + (lane & 15);
            Og[(rbase + qrow) * D_ + col] = f2bf(xacc[n][r] / lrow[r]);
        }
}

// ---------------------------------------------------------------------------
// LN fused v2: y = LN(bf16(Y) + bf16(resid)) * gamma + beta, fp32 out.
// ---------------------------------------------------------------------------
__global__ __launch_bounds__(256) void ln_fused(
    const u16* __restrict__ Yb, const u16* __restrict__ residb,
    const float* __restrict__ g, const float* __restrict__ bt,
    float* __restrict__ out)
{
    __shared__ float red[2][4];
    const int row = blockIdx.x, tid = threadIdx.x;
    u16x4 yv = *(const u16x4*)(Yb + (size_t)row * D_ + tid * 4);
    u16x4 rv = *(const u16x4*)(residb + (size_t)row * D_ + tid * 4);
    float x0 = bf2f(yv[0]) + bf2f(rv[0]);
    float x1 = bf2f(yv[1]) + bf2f(rv[1]);
    float x2 = bf2f(yv[2]) + bf2f(rv[2]);
    float x3 = bf2f(yv[3]) + bf2f(rv[3]);
    float s = x0 + x1 + x2 + x3;
    float q = x0 * x0 + x1 * x1 + x2 * x2 + x3 * x3;
    #pragma unroll
    for (int m = 1; m < 64; m <<= 1) { s += __shfl_xor(s, m); q += __shfl_xor(q, m); }
    const int w = tid >> 6, lane = tid & 63;
    if (lane == 0) { red[0][w] = s; red[1][w] = q; }
    __syncthreads();
    s = red[0][0] + red[0][1] + red[0][2] + red[0][3];
    q = red[1][0] + red[1][1] + red[1][2] + red[1][3];
    float mu = s * (1.f / 1024.f);
    float var = q * (1.f / 1024.f) - mu * mu;
    float rstd = rsqrtf(var + 1e-6f);
    float4 gv = *(const float4*)(g + tid * 4);
    float4 bv = *(const float4*)(bt + tid * 4);
    float4 o;
    o.x = (x0 - mu) * rstd * gv.x + bv.x;
    o.y = (x1 - mu) * rstd * gv.y + bv.y;
    o.z = (x2 - mu) * rstd * gv.z + bv.z;
    o.w = (x3 - mu) * rstd * gv.w + bv.w;
    *(float4*)(out + (size_t)row * D_ + tid * 4) = o;
}

// ---------------------------------------------------------------------------
// LayerNorm in-place on fp32 [4096][1024] (fallback path).
// ---------------------------------------------------------------------------
__global__ __launch_bounds__(256) void ln_inplace(
    float* __restrict__ Y, const float* __restrict__ g, const float* __restrict__ bt)
{
    __shared__ float red[2][4];
    const int row = blockIdx.x, tid = threadIdx.x;
    float4 v = *(const float4*)(Y + (size_t)row * D_ + tid * 4);
    float s = v.x + v.y + v.z + v.w;
    float q = v.x * v.x + v.y * v.y + v.z * v.z + v.w * v.w;
    #pragma unroll
    for (int m = 1; m < 64; m <<= 1) { s += __shfl_xor(s, m); q += __shfl_xor(q, m); }
    const int w = tid >> 6, lane = tid & 63;
    if (lane == 0) { red[0][w] = s; red[1][w] = q; }
    __syncthreads();
    s = red[0][0] + red[0][1] + red[0][2] + red[0][3];
    q = red[1][0] + red[1][1] + red[1][2] + red[1][3];
    float mu = s * (1.f / 1024.f);
    float var = q * (1.f / 1024.f) - mu * mu;
    float rstd = rsqrtf(var + 1e-6f);
    float4 gv = *(const float4*)(g + tid * 4);
    float4 bv = *(const float4*)(bt + tid * 4);
    v.x = (v.x - mu) * rstd * gv.x + bv.x;
    v.y = (v.y - mu) * rstd * gv.y + bv.y;
    v.z = (v.z - mu) * rstd * gv.z + bv.z;
    v.w = (v.w - mu) * rstd * gv.w + bv.w;
    *(float4*)(Y + (size_t)row * D_ + tid * 4) = v;
}

extern "C" void kernel_launch(void* const* d_in, const int* in_sizes, int n_in,
                              void* d_out, int out_size, void* d_ws, size_t ws_size,
                              hipStream_t stream)
{
    const float* query = (const float*)d_in[0];
    const float* key   = (const float*)d_in[1];
    const float* value = (const float*)d_in[2];
    const float* Wq    = (const float*)d_in[3];
    const float* Wk    = (const float*)d_in[4];
    const float* Wv    = (const float*)d_in[5];
    const float* Wo    = (const float*)d_in[6];
    const float* gamma = (const float*)d_in[7];
    const float* beta  = (const float*)d_in[8];
    float* out = (float*)d_out;

    const size_t ACT = (size_t)MROWS * D_;
    const size_t WSZ = (size_t)D_ * D_;
    const size_t NEED = (3 * ACT + 4 * WSZ + 3 * ACT) * 2;   // 58,720,256 B

    if (ws_size >= NEED) {
        // layout (bf16): actb = [q-packed | k-packed | v-packed] | wb | pb
        // After QKV gemm: k,v-packed dead. q-packed KEPT as bf16 residual.
        //   Ap (attn out) -> v region; Yb (Wo out) -> k region.
        u16* actb = (u16*)d_ws;
        u16* wb   = actb + 3 * ACT;
        u16* pb   = wb + 4 * WSZ;      // Qp | Kp | Vt (transposed)
        u16* Ap   = actb + 2 * ACT;
        u16* Yb   = actb + ACT;

        pack_bf16<<<2048, 256, 0, stream>>>(query, key, value, Wq, Wk, Wv, Wo, actb, wb);
        gemm_qkv8<<<dim3(8, 32, 3), 512, 0, stream>>>(actb, wb, pb);
        attn_fwd6<<<512, 512, 0, stream>>>(pb, pb + ACT, pb + 2 * ACT, Ap);
        gemm_fast<64, false, false><<<dim3(8, 64, 1), 256, 0, stream>>>(Ap, wb + 3 * WSZ, Yb, nullptr, nullptr);
        ln_fused<<<MROWS, 256, 0, stream>>>(Yb, actb, gamma, beta, out);
    } else {
        u16* Qp = (u16*)d_ws;
        u16* Kp = Qp + ACT;
        u16* Vp = Kp + ACT;
        u16* Ap = Vp + ACT;
        dim3 gg(D_ / 128, MROWS / 128);
        gemm_bt<false, false><<<gg, 256, 0, stream>>>(query, Wq, Qp, nullptr, nullptr, MROWS, D_, D_);
        gemm_bt<false, false><<<gg, 256, 0, stream>>>(key,   Wk, Kp, nullptr, nullptr, MROWS, D_, D_);
        gemm_bt<false, false><<<gg, 256, 0, stream>>>(value, Wv, Vp, nullptr, nullptr, MROWS, D_, D_);
        attn_fwd<<<dim3(S_ / 64, H_, B_), 256, 0, stream>>>(Qp, Kp, Vp, Ap);
        gemm_bt<true, true><<<gg, 256, 0, stream>>>(Ap, Wo, nullptr, out, query, MROWS, D_, D_);
        ln_inplace<<<MROWS, 256, 0, stream>>>(out, gamma, beta);
    }
}

// Round 16
// 105.957 us; speedup vs baseline: 1.6346x; 1.0001x over previous
//
#include <hip/hip_runtime.h>
#include <hip/hip_bf16.h>

// Fused MHA block: y = LN(x @ attn + residual)
// B=4 S=1024 D=1024 H=16 DK=64. fp32 I/O, bf16 MFMA internally.
#define B_ 4
#define S_ 1024
#define D_ 1024
#define H_ 16
#define DK_ 64
#define MROWS (B_*S_)   // 4096

typedef short bf16x8 __attribute__((ext_vector_type(8)));
typedef float f32x4 __attribute__((ext_vector_type(4)));
typedef unsigned short u16;
typedef unsigned u32;
typedef u16 u16x4 __attribute__((ext_vector_type(4)));

__device__ __forceinline__ u16 f2bf(float f) {
    union { float f; unsigned u; } v; v.f = f;
    unsigned u = v.u;
    u += 0x7fff + ((u >> 16) & 1);   // RNE
    return (u16)(u >> 16);
}
__device__ __forceinline__ float bf2f(u16 h) {
    union { unsigned u; float f; } v; v.u = ((unsigned)h) << 16;
    return v.f;
}

__device__ __forceinline__ void gld_lds16(const u16* gp, u16* lp) {
    __builtin_amdgcn_global_load_lds(
        (const __attribute__((address_space(1))) void*)gp,
        (__attribute__((address_space(3))) void*)lp,
        16, 0, 0);
}

// ---------------------------------------------------------------------------
// Pack: fp32 -> bf16 for activations and weights (R6-verified).
// ---------------------------------------------------------------------------
__global__ __launch_bounds__(256) void pack_bf16(
    const float* __restrict__ q, const float* __restrict__ k, const float* __restrict__ v,
    const float* __restrict__ wq, const float* __restrict__ wk,
    const float* __restrict__ wv, const float* __restrict__ wo,
    u16* __restrict__ act_dst, u16* __restrict__ w_dst)
{
    const int NACT = 3 * MROWS * D_;
    const int NW   = 4 * D_ * D_;
    for (int c = blockIdx.x * blockDim.x + threadIdx.x;
         c < (NACT + NW) / 4; c += gridDim.x * blockDim.x) {
        int e = c * 4;
        const float* s; u16* d;
        if (e < NACT) {
            int t = e >> 22;
            int off = e & (4194304 - 1);
            s = (t == 0 ? q : t == 1 ? k : v) + off;
            d = act_dst + e;
        } else {
            int e2 = e - NACT;
            int t = e2 >> 20;
            int off = e2 & (1048576 - 1);
            s = (t == 0 ? wq : t == 1 ? wk : t == 2 ? wv : wo) + off;
            d = w_dst + e2;
        }
        float4 tv = *(const float4*)s;
        u16x4 o; o[0]=f2bf(tv.x); o[1]=f2bf(tv.y); o[2]=f2bf(tv.z); o[3]=f2bf(tv.w);
        *(u16x4*)d = o;
    }
}

// ---------------------------------------------------------------------------
// QKV GEMM v6 (R15-verified): 8 waves, 128x128, wave grid 4m x 2n,
// A-reg-preload + B-dbuf, 48KB LDS -> 24 waves/CU.
// z==2 (V projection) stores C transposed (Vt[d][token]).
// ---------------------------------------------------------------------------
__global__ __launch_bounds__(512) void gemm_qkv8(
    const u16* __restrict__ Ab, const u16* __restrict__ Wb,
    u16* __restrict__ Cb)
{
    __shared__ u16 ldsA[128 * 64];        // 16KB
    __shared__ u16 ldsB[2][128 * 64];     // 32KB

    const int gx = gridDim.x, gy = gridDim.y;
    const int nwg = gx * gy * gridDim.z;
    const int flat = blockIdx.x + gx * (blockIdx.y + gy * blockIdx.z);
    const int f = (flat & 7) * (nwg >> 3) + (flat >> 3);
    const int bx = f % gx;
    const int rem = f / gx;
    const int by = rem % gy;
    const int z = rem / gy;

    Ab += (size_t)z * MROWS * D_;
    Wb += (size_t)z * D_ * D_;

    const int tid = threadIdx.x, lane = tid & 63, wid = tid >> 6;
    const int wr = wid >> 1, wc = wid & 1;                          // 4m x 2n
    const int g = lane >> 4, ql = lane & 15;
    const int m0 = by * 128, n0 = bx * 128;

    auto stageA = [&](int it) {
        const int kt = it * 64;
        #pragma unroll
        for (int j = 0; j < 2; ++j) {
            int ch = j * 512 + tid;
            int row = ch >> 3, c8 = (ch & 7) ^ (row & 7);
            gld_lds16(Ab + (size_t)(m0 + row) * 1024 + kt + c8 * 8,
                      &ldsA[(j * 512 + wid * 64) * 8]);
        }
    };
    auto stageB = [&](int p, int it) {
        const int kt = it * 64;
        #pragma unroll
        for (int j = 0; j < 2; ++j) {
            int ch = j * 512 + tid;
            int row = ch >> 3, c8 = (ch & 7) ^ (row & 7);
            gld_lds16(Wb + (size_t)(n0 + row) * 1024 + kt + c8 * 8,
                      &ldsB[p][(j * 512 + wid * 64) * 8]);
        }
    };

    f32x4 acc[2][4] = {};

    stageA(0);
    stageB(0, 0);
    __syncthreads();

    for (int it = 0; it < 16; ++it) {
        const int bcur = it & 1;

        bf16x8 af[2][2];
        #pragma unroll
        for (int ks = 0; ks < 2; ++ks) {
            const int cb = ks * 32 + g * 8;
            #pragma unroll
            for (int m = 0; m < 2; ++m) {
                int row = wr * 32 + m * 16 + ql;
                af[ks][m] = *(const bf16x8*)(&ldsA[row * 64 + (cb ^ ((row & 7) << 3))]);
            }
        }
        __syncthreads();

        if (it < 15) {
            stageA(it + 1);
            stageB(bcur ^ 1, it + 1);
        }
        __builtin_amdgcn_sched_barrier(0);

        #pragma unroll
        for (int ks = 0; ks < 2; ++ks) {
            const int cb = ks * 32 + g * 8;
            bf16x8 bfr[4];
            #pragma unroll
            for (int n = 0; n < 4; ++n) {
                int row = wc * 64 + n * 16 + ql;
                bfr[n] = *(const bf16x8*)(&ldsB[bcur][row * 64 + (cb ^ ((row & 7) << 3))]);
            }
            #pragma unroll
            for (int m = 0; m < 2; ++m)
                #pragma unroll
                for (int n = 0; n < 4; ++n)
                    acc[m][n] = __builtin_amdgcn_mfma_f32_16x16x32_bf16(
                        af[ks][m], bfr[n], acc[m][n], 0, 0, 0);
        }

        __syncthreads();
    }

    if (z == 2) {
        u16* Cz = Cb + 2 * (size_t)MROWS * D_;
        #pragma unroll
        for (int m = 0; m < 2; ++m)
            #pragma unroll
            for (int n = 0; n < 4; ++n) {
                u16x4 o;
                #pragma unroll
                for (int r = 0; r < 4; ++r) o[r] = f2bf(acc[m][n][r]);
                int grow = m0 + wr * 32 + m * 16 + g * 4;   // token
                int gcol = n0 + wc * 64 + n * 16 + ql;      // d
                *(u16x4*)(&Cz[(size_t)gcol * MROWS + grow]) = o;
            }
    } else {
        u16* Cz = Cb + (size_t)z * MROWS * D_;
        #pragma unroll
        for (int m = 0; m < 2; ++m)
            #pragma unroll
            for (int n = 0; n < 4; ++n)
                #pragma unroll
                for (int r = 0; r < 4; ++r) {
                    int grow = m0 + wr * 32 + m * 16 + g * 4 + r;
                    int gcol = n0 + wc * 64 + n * 16 + ql;
                    Cz[(size_t)grow * 1024 + gcol] = f2bf(acc[m][n][r]);
                }
    }
}

// ---------------------------------------------------------------------------
// Wo GEMM, 8-wave (NEW): 64x128 tile, 512 thr, wave grid 2m x 4n (each wave
// 32x32, acc 2x2). Same verified skeleton; LDS = 8+32 = 40KB -> 4 blocks/CU
// = 32 waves/CU. bf16 C out (Yb).
// ---------------------------------------------------------------------------
__global__ __launch_bounds__(512) void gemm_wo8(
    const u16* __restrict__ Ab, const u16* __restrict__ Wb,
    u16* __restrict__ Cb)
{
    __shared__ u16 ldsA[64 * 64];         // 8KB
    __shared__ u16 ldsB[2][128 * 64];     // 32KB

    // XCD-chunked remap (nwg = 512, %8==0 -> bijective)
    const int gx = gridDim.x, gy = gridDim.y;
    const int nwg = gx * gy;
    const int flat = blockIdx.x + gx * blockIdx.y;
    const int f = (flat & 7) * (nwg >> 3) + (flat >> 3);
    const int bx = f % gx;
    const int by = f / gx;

    const int tid = threadIdx.x, lane = tid & 63, wid = tid >> 6;
    const int wr = wid >> 2, wc = wid & 3;                          // 2m x 4n
    const int g = lane >> 4, ql = lane & 15;
    const int m0 = by * 64, n0 = bx * 128;

    auto stageA = [&](int it) {
        const int kt = it * 64;
        int ch = tid;                    // 512 chunks cover 64x64
        int row = ch >> 3, c8 = (ch & 7) ^ (row & 7);
        gld_lds16(Ab + (size_t)(m0 + row) * 1024 + kt + c8 * 8,
                  &ldsA[(wid * 64) * 8]);
    };
    auto stageB = [&](int p, int it) {
        const int kt = it * 64;
        #pragma unroll
        for (int j = 0; j < 2; ++j) {
            int ch = j * 512 + tid;
            int row = ch >> 3, c8 = (ch & 7) ^ (row & 7);
            gld_lds16(Wb + (size_t)(n0 + row) * 1024 + kt + c8 * 8,
                      &ldsB[p][(j * 512 + wid * 64) * 8]);
        }
    };

    f32x4 acc[2][2] = {};

    stageA(0);
    stageB(0, 0);
    __syncthreads();

    for (int it = 0; it < 16; ++it) {
        const int bcur = it & 1;

        bf16x8 af[2][2];
        #pragma unroll
        for (int ks = 0; ks < 2; ++ks) {
            const int cb = ks * 32 + g * 8;
            #pragma unroll
            for (int m = 0; m < 2; ++m) {
                int row = wr * 32 + m * 16 + ql;
                af[ks][m] = *(const bf16x8*)(&ldsA[row * 64 + (cb ^ ((row & 7) << 3))]);
            }
        }
        __syncthreads();

        if (it < 15) {
            stageA(it + 1);
            stageB(bcur ^ 1, it + 1);
        }
        __builtin_amdgcn_sched_barrier(0);

        #pragma unroll
        for (int ks = 0; ks < 2; ++ks) {
            const int cb = ks * 32 + g * 8;
            bf16x8 bfr[2];
            #pragma unroll
            for (int n = 0; n < 2; ++n) {
                int row = wc * 32 + n * 16 + ql;
                bfr[n] = *(const bf16x8*)(&ldsB[bcur][row * 64 + (cb ^ ((row & 7) << 3))]);
            }
            #pragma unroll
            for (int m = 0; m < 2; ++m)
                #pragma unroll
                for (int n = 0; n < 2; ++n)
                    acc[m][n] = __builtin_amdgcn_mfma_f32_16x16x32_bf16(
                        af[ks][m], bfr[n], acc[m][n], 0, 0, 0);
        }

        __syncthreads();
    }

    // C/D map: col = lane&15, row = (lane>>4)*4 + reg
    #pragma unroll
    for (int m = 0; m < 2; ++m)
        #pragma unroll
        for (int n = 0; n < 2; ++n)
            #pragma unroll
            for (int r = 0; r < 4; ++r) {
                int grow = m0 + wr * 32 + m * 16 + g * 4 + r;
                int gcol = n0 + wc * 32 + n * 16 + ql;
                Cb[(size_t)grow * 1024 + gcol] = f2bf(acc[m][n][r]);
            }
}

// ---------------------------------------------------------------------------
// Fallback GEMM (round-1 path), unchanged.
// ---------------------------------------------------------------------------
template<bool A_BF16, bool EPI_RESID>
__global__ __launch_bounds__(256) void gemm_bt(
    const void* __restrict__ Av, const float* __restrict__ Bw,
    u16* __restrict__ Cb, float* __restrict__ Cf,
    const float* __restrict__ resid, int M, int N, int K)
{
    __shared__ u16 lds[2][128 * 64];
    const int tid  = threadIdx.x;
    const int lane = tid & 63;
    const int wid  = tid >> 6;
    const int wr = wid >> 1, wc = wid & 1;
    const int m0 = blockIdx.y * 128, n0 = blockIdx.x * 128;

    f32x4 acc[4][4] = {};

    for (int kt = 0; kt < K; kt += 64) {
        #pragma unroll
        for (int j = 0; j < 8; ++j) {
            int idx4 = tid + 256 * j;
            int r = idx4 >> 4;
            int c = (idx4 & 15) * 4;
            u16x4 aw, bw;
            if (A_BF16) {
                const u16* Ab2 = (const u16*)Av;
                aw = *(const u16x4*)(Ab2 + (size_t)(m0 + r) * K + kt + c);
            } else {
                const float* Af = (const float*)Av;
                float4 t = *(const float4*)(Af + (size_t)(m0 + r) * K + kt + c);
                aw[0] = f2bf(t.x); aw[1] = f2bf(t.y); aw[2] = f2bf(t.z); aw[3] = f2bf(t.w);
            }
            {
                float4 t = *(const float4*)(Bw + (size_t)(n0 + r) * K + kt + c);
                bw[0] = f2bf(t.x); bw[1] = f2bf(t.y); bw[2] = f2bf(t.z); bw[3] = f2bf(t.w);
            }
            int sa = r * 64 + (c ^ ((r & 7) << 3));
            *(u16x4*)(&lds[0][sa]) = aw;
            *(u16x4*)(&lds[1][sa]) = bw;
        }
        __syncthreads();
        #pragma unroll
        for (int ks = 0; ks < 2; ++ks) {
            const int cb = ks * 32 + (lane >> 4) * 8;
            bf16x8 af[4], bfr[4];
            #pragma unroll
            for (int m = 0; m < 4; ++m) {
                int row = wr * 64 + m * 16 + (lane & 15);
                af[m] = *(const bf16x8*)(&lds[0][row * 64 + (cb ^ ((row & 7) << 3))]);
            }
            #pragma unroll
            for (int n = 0; n < 4; ++n) {
                int row = wc * 64 + n * 16 + (lane & 15);
                bfr[n] = *(const bf16x8*)(&lds[1][row * 64 + (cb ^ ((row & 7) << 3))]);
            }
            #pragma unroll
            for (int m = 0; m < 4; ++m)
                #pragma unroll
                for (int n = 0; n < 4; ++n)
                    acc[m][n] = __builtin_amdgcn_mfma_f32_16x16x32_bf16(
                        af[m], bfr[n], acc[m][n], 0, 0, 0);
        }
        __syncthreads();
    }

    #pragma unroll
    for (int m = 0; m < 4; ++m)
        #pragma unroll
        for (int n = 0; n < 4; ++n)
            #pragma unroll
            for (int r = 0; r < 4; ++r) {
                int grow = m0 + wr * 64 + m * 16 + (lane >> 4) * 4 + r;
                int gcol = n0 + wc * 64 + n * 16 + (lane & 15);
                float v = acc[m][n][r];
                if (EPI_RESID)
                    Cf[(size_t)grow * N + gcol] = v + resid[(size_t)grow * N + gcol];
                else
                    Cb[(size_t)grow * N + gcol] = f2bf(v);
            }
}

// ---------------------------------------------------------------------------
// Flash attention v6 (R9-verified): swapped QK^T, in-lane softmax,
// wave-private P, Vt-from-global, split-stage pipeline, Q-in-reg, defer-max.
// ---------------------------------------------------------------------------
__global__ __launch_bounds__(512, 4) void attn_fwd6(
    const u16* __restrict__ Qg, const u16* __restrict__ Kg,
    const u16* __restrict__ Vt, u16* __restrict__ Og)
{
    __shared__ u16 ks2[64 * 64];
    __shared__ u16 vsT[64 * 64];
    __shared__ u16 ps[128 * 64];

    const int tid = threadIdx.x, lane = tid & 63, w = tid >> 6;
    const int g = lane >> 4, ql = lane & 15;

    const int bid = blockIdx.x;
    const int f = (bid & 7) * 64 + (bid >> 3);
    const int qt = f & 7, h = (f >> 3) & 15, b = f >> 7;
    const int q0 = qt * 128;
    const size_t rbase = (size_t)b * S_;
    const int cb0 = h * DK_;

    bf16x8 qb[2];
    {
        const u16* qp = Qg + (rbase + q0 + w * 16 + ql) * D_ + cb0 + 8 * g;
        qb[0] = *(const bf16x8*)(qp);
        qb[1] = *(const bf16x8*)(qp + 32);
    }

    auto stage_k = [&](int kv0) {
        int row = tid >> 3, c8 = (tid & 7) ^ (row & 7);
        gld_lds16(Kg + (rbase + kv0 + row) * D_ + cb0 + c8 * 8, &ks2[w * 512]);
    };
    auto stage_v = [&](int kv0) {
        int row = tid >> 3, c8 = (tid & 7) ^ (row & 7);
        gld_lds16(Vt + (size_t)(cb0 + row) * MROWS + rbase + kv0 + c8 * 8, &vsT[w * 512]);
    };

    stage_k(0);
    stage_v(0);
    __syncthreads();

    float mrow = -1e30f, lrow = 0.f;
    f32x4 xacc[4] = {};

    for (int jt = 0; jt < 16; ++jt) {
        f32x4 sacc[4] = {};
        __builtin_amdgcn_s_setprio(1);
        #pragma unroll
        for (int ks = 0; ks < 2; ++ks) {
            #pragma unroll
            for (int n = 0; n < 4; ++n) {
                int krow = n * 16 + ql;
                int c = 32 * ks + 8 * g;
                bf16x8 kf = *(const bf16x8*)(&ks2[krow * 64 + (c ^ ((krow & 7) << 3))]);
                sacc[n] = __builtin_amdgcn_mfma_f32_16x16x32_bf16(kf, qb[ks], sacc[n], 0, 0, 0);
            }
        }
        __builtin_amdgcn_s_setprio(0);

        __syncthreads();
        if (jt < 15) stage_k((jt + 1) * 64);

        float mt = sacc[0][0];
        #pragma unroll
        for (int n = 0; n < 4; ++n)
            #pragma unroll
            for (int r = 0; r < 4; ++r) mt = fmaxf(mt, sacc[n][r]);
        mt = fmaxf(mt, __shfl_xor(mt, 16));
        mt = fmaxf(mt, __shfl_xor(mt, 32));
        if (!__all(mt * 0.125f - mrow <= 8.f)) {
            float mnew = fmaxf(mrow, mt * 0.125f);
            float alpha = __expf(mrow - mnew);
            mrow = mnew;
            lrow *= alpha;
            #pragma unroll
            for (int r = 0; r < 4; ++r) {
                float a_r = __shfl(alpha, 4 * g + r);
                #pragma unroll
                for (int n2 = 0; n2 < 4; ++n2) xacc[n2][r] *= a_r;
            }
        }
        float rsum = 0.f;
        u16 pb[16];
        #pragma unroll
        for (int n = 0; n < 4; ++n)
            #pragma unroll
            for (int r = 0; r < 4; ++r) {
                float p = __expf(sacc[n][r] * 0.125f - mrow);
                rsum += p;
                pb[n * 4 + r] = f2bf(p);
            }
        rsum += __shfl_xor(rsum, 16);
        rsum += __shfl_xor(rsum, 32);
        lrow += rsum;

        {
            const int q = w * 16 + ql;
            #pragma unroll
            for (int n = 0; n < 4; ++n) {
                int c = 16 * n + 4 * g;
                *(u16x4*)(&ps[q * 64 + (c ^ ((q & 7) << 3))]) = *(const u16x4*)(&pb[n * 4]);
            }
        }
        asm volatile("s_waitcnt lgkmcnt(0)" ::: "memory");
        __builtin_amdgcn_sched_barrier(0);

        bf16x8 pa[2];
        {
            const int q = w * 16 + ql;
            #pragma unroll
            for (int ks = 0; ks < 2; ++ks) {
                int c = 32 * ks + 8 * g;
                pa[ks] = *(const bf16x8*)(&ps[q * 64 + (c ^ ((q & 7) << 3))]);
            }
        }

        __builtin_amdgcn_s_setprio(1);
        #pragma unroll
        for (int ks = 0; ks < 2; ++ks)
            #pragma unroll
            for (int n2 = 0; n2 < 4; ++n2) {
                int vrow = n2 * 16 + ql;
                int c2 = 32 * ks + 8 * g;
                bf16x8 bv = *(const bf16x8*)(&vsT[vrow * 64 + (c2 ^ ((vrow & 7) << 3))]);
                xacc[n2] = __builtin_amdgcn_mfma_f32_16x16x32_bf16(pa[ks], bv, xacc[n2], 0, 0, 0);
            }
        __builtin_amdgcn_s_setprio(0);

        __syncthreads();
        if (jt < 15) stage_v((jt + 1) * 64);
    }

    float linv[4];
    #pragma unroll
    for (int r = 0; r < 4; ++r) linv[r] = 1.f / __shfl(lrow, 4 * g + r);
    #pragma unroll
    for (int n2 = 0; n2 < 4; ++n2)
        #pragma unroll
        for (int r = 0; r < 4; ++r) {
            int qrow = q0 + w * 16 + 4 * g + r;
            int col = cb0 + n2 * 16 + ql;
            Og[(rbase + qrow) * D_ + col] = f2bf(xacc[n2][r] * linv[r]);
        }
}

// ---------------------------------------------------------------------------
// Flash attention (R2-verified version) for the fallback path.
// ---------------------------------------------------------------------------
__global__ __launch_bounds__(256) void attn_fwd(
    const u16* __restrict__ Qg, const u16* __restrict__ Kg,
    const u16* __restrict__ Vg, u16* __restrict__ Og)
{
    __shared__ u16 qs[64 * 64], ks2[64 * 64], vt[64 * 64], ps[64 * 64];
    const int tid = threadIdx.x, lane = tid & 63, w = tid >> 6;
    const int b = blockIdx.z, h = blockIdx.y, q0 = blockIdx.x * 64;
    const size_t rbase = (size_t)b * S_;
    const int cb0 = h * DK_;

    #pragma unroll
    for (int j = 0; j < 4; ++j) {
        int idx4 = tid + 256 * j;
        int r = idx4 >> 4, c = (idx4 & 15) * 4;
        u16x4 t = *(const u16x4*)(Qg + (rbase + q0 + r) * D_ + cb0 + c);
        *(u16x4*)(&qs[r * 64 + (c ^ ((r & 7) << 3))]) = t;
    }

    float mrow[4], lrow[4];
    f32x4 xacc[4] = {};
    #pragma unroll
    for (int r = 0; r < 4; ++r) { mrow[r] = -1e30f; lrow[r] = 0.f; }

    for (int jt = 0; jt < 16; ++jt) {
        const int kv0 = jt * 64;
        __syncthreads();
        #pragma unroll
        for (int j = 0; j < 4; ++j) {
            int idx4 = tid + 256 * j;
            int r = idx4 >> 4, c = (idx4 & 15) * 4;
            u16x4 t = *(const u16x4*)(Kg + (rbase + kv0 + r) * D_ + cb0 + c);
            *(u16x4*)(&ks2[r * 64 + (c ^ ((r & 7) << 3))]) = t;
            u16x4 tv = *(const u16x4*)(Vg + (rbase + kv0 + r) * D_ + cb0 + c);
            #pragma unroll
            for (int jj = 0; jj < 4; ++jj) {
                int d = c + jj;
                vt[d * 64 + (r ^ ((d & 7) << 3))] = tv[jj];
            }
        }
        __syncthreads();

        f32x4 sacc[4] = {};
        #pragma unroll
        for (int ks = 0; ks < 2; ++ks) {
            const int cb = ks * 32 + (lane >> 4) * 8;
            int qrow = w * 16 + (lane & 15);
            bf16x8 aq = *(const bf16x8*)(&qs[qrow * 64 + (cb ^ ((qrow & 7) << 3))]);
            #pragma unroll
            for (int n = 0; n < 4; ++n) {
                int krow = n * 16 + (lane & 15);
                bf16x8 bk = *(const bf16x8*)(&ks2[krow * 64 + (cb ^ ((krow & 7) << 3))]);
                sacc[n] = __builtin_amdgcn_mfma_f32_16x16x32_bf16(aq, bk, sacc[n], 0, 0, 0);
            }
        }

        #pragma unroll
        for (int r = 0; r < 4; ++r) {
            float mx = fmaxf(fmaxf(sacc[0][r], sacc[1][r]),
                             fmaxf(sacc[2][r], sacc[3][r]));
            mx = fmaxf(mx, __shfl_xor(mx, 1));
            mx = fmaxf(mx, __shfl_xor(mx, 2));
            mx = fmaxf(mx, __shfl_xor(mx, 4));
            mx = fmaxf(mx, __shfl_xor(mx, 8));
            float mnew = fmaxf(mrow[r], mx * 0.125f);
            float alpha = __expf(mrow[r] - mnew);
            float p[4], rsum = 0.f;
            #pragma unroll
            for (int n = 0; n < 4; ++n) { p[n] = __expf(sacc[n][r] * 0.125f - mnew); rsum += p[n]; }
            rsum += __shfl_xor(rsum, 1);
            rsum += __shfl_xor(rsum, 2);
            rsum += __shfl_xor(rsum, 4);
            rsum += __shfl_xor(rsum, 8);
            lrow[r] = lrow[r] * alpha + rsum;
            mrow[r] = mnew;
            int qrow = w * 16 + (lane >> 4) * 4 + r;
            #pragma unroll
            for (int n = 0; n < 4; ++n) {
                xacc[n][r] *= alpha;
                int col = n * 16 + (lane & 15);
                ps[qrow * 64 + (col ^ ((qrow & 7) << 3))] = f2bf(p[n]);
            }
        }
        __syncthreads();

        #pragma unroll
        for (int ks = 0; ks < 2; ++ks) {
            const int cb = ks * 32 + (lane >> 4) * 8;
            int prow = w * 16 + (lane & 15);
            bf16x8 ap = *(const bf16x8*)(&ps[prow * 64 + (cb ^ ((prow & 7) << 3))]);
            #pragma unroll
            for (int n = 0; n < 4; ++n) {
                int vrow = n * 16 + (lane & 15);
                bf16x8 bv = *(const bf16x8*)(&vt[vrow * 64 + (cb ^ ((vrow & 7) << 3))]);
                xacc[n] = __builtin_amdgcn_mfma_f32_16x16x32_bf16(ap, bv, xacc[n], 0, 0, 0);
            }
        }
    }

    #pragma unroll
    for (int n = 0; n < 4; ++n)
        #pragma unroll
        for (int r = 0; r < 4; ++r) {
            int qrow = q0 + w * 16 + (lane >> 4) * 4 + r;
            int col = cb0 + n * 16 + (lane & 15);
            Og[(rbase + qrow) * D_ + col] = f2bf(xacc[n][r] / lrow[r]);
        }
}

// ---------------------------------------------------------------------------
// LN fused v2: y = LN(bf16(Y) + bf16(resid)) * gamma + beta, fp32 out.
// ---------------------------------------------------------------------------
__global__ __launch_bounds__(256) void ln_fused(
    const u16* __restrict__ Yb, const u16* __restrict__ residb,
    const float* __restrict__ g, const float* __restrict__ bt,
    float* __restrict__ out)
{
    __shared__ float red[2][4];
    const int row = blockIdx.x, tid = threadIdx.x;
    u16x4 yv = *(const u16x4*)(Yb + (size_t)row * D_ + tid * 4);
    u16x4 rv = *(const u16x4*)(residb + (size_t)row * D_ + tid * 4);
    float x0 = bf2f(yv[0]) + bf2f(rv[0]);
    float x1 = bf2f(yv[1]) + bf2f(rv[1]);
    float x2 = bf2f(yv[2]) + bf2f(rv[2]);
    float x3 = bf2f(yv[3]) + bf2f(rv[3]);
    float s = x0 + x1 + x2 + x3;
    float q = x0 * x0 + x1 * x1 + x2 * x2 + x3 * x3;
    #pragma unroll
    for (int m = 1; m < 64; m <<= 1) { s += __shfl_xor(s, m); q += __shfl_xor(q, m); }
    const int w = tid >> 6, lane = tid & 63;
    if (lane == 0) { red[0][w] = s; red[1][w] = q; }
    __syncthreads();
    s = red[0][0] + red[0][1] + red[0][2] + red[0][3];
    q = red[1][0] + red[1][1] + red[1][2] + red[1][3];
    float mu = s * (1.f / 1024.f);
    float var = q * (1.f / 1024.f) - mu * mu;
    float rstd = rsqrtf(var + 1e-6f);
    float4 gv = *(const float4*)(g + tid * 4);
    float4 bv = *(const float4*)(bt + tid * 4);
    float4 o;
    o.x = (x0 - mu) * rstd * gv.x + bv.x;
    o.y = (x1 - mu) * rstd * gv.y + bv.y;
    o.z = (x2 - mu) * rstd * gv.z + bv.z;
    o.w = (x3 - mu) * rstd * gv.w + bv.w;
    *(float4*)(out + (size_t)row * D_ + tid * 4) = o;
}

// ---------------------------------------------------------------------------
// LayerNorm in-place on fp32 [4096][1024] (fallback path).
// ---------------------------------------------------------------------------
__global__ __launch_bounds__(256) void ln_inplace(
    float* __restrict__ Y, const float* __restrict__ g, const float* __restrict__ bt)
{
    __shared__ float red[2][4];
    const int row = blockIdx.x, tid = threadIdx.x;
    float4 v = *(const float4*)(Y + (size_t)row * D_ + tid * 4);
    float s = v.x + v.y + v.z + v.w;
    float q = v.x * v.x + v.y * v.y + v.z * v.z + v.w * v.w;
    #pragma unroll
    for (int m = 1; m < 64; m <<= 1) { s += __shfl_xor(s, m); q += __shfl_xor(q, m); }
    const int w = tid >> 6, lane = tid & 63;
    if (lane == 0) { red[0][w] = s; red[1][w] = q; }
    __syncthreads();
    s = red[0][0] + red[0][1] + red[0][2] + red[0][3];
    q = red[1][0] + red[1][1] + red[1][2] + red[1][3];
    float mu = s * (1.f / 1024.f);
    float var = q * (1.f / 1024.f) - mu * mu;
    float rstd = rsqrtf(var + 1e-6f);
    float4 gv = *(const float4*)(g + tid * 4);
    float4 bv = *(const float4*)(bt + tid * 4);
    v.x = (v.x - mu) * rstd * gv.x + bv.x;
    v.y = (v.y - mu) * rstd * gv.y + bv.y;
    v.z = (v.z - mu) * rstd * gv.z + bv.z;
    v.w = (v.w - mu) * rstd * gv.w + bv.w;
    *(float4*)(Y + (size_t)row * D_ + tid * 4) = v;
}

extern "C" void kernel_launch(void* const* d_in, const int* in_sizes, int n_in,
                              void* d_out, int out_size, void* d_ws, size_t ws_size,
                              hipStream_t stream)
{
    const float* query = (const float*)d_in[0];
    const float* key   = (const float*)d_in[1];
    const float* value = (const float*)d_in[2];
    const float* Wq    = (const float*)d_in[3];
    const float* Wk    = (const float*)d_in[4];
    const float* Wv    = (const float*)d_in[5];
    const float* Wo    = (const float*)d_in[6];
    const float* gamma = (const float*)d_in[7];
    const float* beta  = (const float*)d_in[8];
    float* out = (float*)d_out;

    const size_t ACT = (size_t)MROWS * D_;
    const size_t WSZ = (size_t)D_ * D_;
    const size_t NEED = (3 * ACT + 4 * WSZ + 3 * ACT) * 2;   // 58,720,256 B

    if (ws_size >= NEED) {
        // layout (bf16): actb = [q-packed | k-packed | v-packed] | wb | pb
        // After QKV gemm: k,v-packed dead. q-packed KEPT as bf16 residual.
        //   Ap (attn out) -> v region; Yb (Wo out) -> k region.
        u16* actb = (u16*)d_ws;
        u16* wb   = actb + 3 * ACT;
        u16* pb   = wb + 4 * WSZ;      // Qp | Kp | Vt (transposed)
        u16* Ap   = actb + 2 * ACT;
        u16* Yb   = actb + ACT;

        pack_bf16<<<2048, 256, 0, stream>>>(query, key, value, Wq, Wk, Wv, Wo, actb, wb);
        gemm_qkv8<<<dim3(8, 32, 3), 512, 0, stream>>>(actb, wb, pb);
        attn_fwd6<<<512, 512, 0, stream>>>(pb, pb + ACT, pb + 2 * ACT, Ap);
        gemm_wo8<<<dim3(8, 64), 512, 0, stream>>>(Ap, wb + 3 * WSZ, Yb);
        ln_fused<<<MROWS, 256, 0, stream>>>(Yb, actb, gamma, beta, out);
    } else {
        u16* Qp = (u16*)d_ws;
        u16* Kp = Qp + ACT;
        u16* Vp = Kp + ACT;
        u16* Ap = Vp + ACT;
        dim3 gg(D_ / 128, MROWS / 128);
        gemm_bt<false, false><<<gg, 256, 0, stream>>>(query, Wq, Qp, nullptr, nullptr, MROWS, D_, D_);
        gemm_bt<false, false><<<gg, 256, 0, stream>>>(key,   Wk, Kp, nullptr, nullptr, MROWS, D_, D_);
        gemm_bt<false, false><<<gg, 256, 0, stream>>>(value, Wv, Vp, nullptr, nullptr, MROWS, D_, D_);
        attn_fwd<<<dim3(S_ / 64, H_, B_), 256, 0, stream>>>(Qp, Kp, Vp, Ap);
        gemm_bt<true, true><<<gg, 256, 0, stream>>>(Ap, Wo, nullptr, out, query, MROWS, D_, D_);
        ln_inplace<<<MROWS, 256, 0, stream>>>(out, gamma, beta);
    }
}